// Round 10
// baseline (669.469 us; speedup 1.0000x reference)
//
#include <hip/hip_runtime.h>
#include <hip/hip_bf16.h>
#include <hip/hip_fp8.h>

#define B_ 16
#define C_ 2048
#define N_ 256
#define HEADS_ 4
#define D_ 512

typedef unsigned int u32;
typedef unsigned char u8;
typedef unsigned short ushort_t;
typedef __attribute__((ext_vector_type(8))) short bfx8;
typedef __attribute__((ext_vector_type(4))) float fx4;

__device__ __forceinline__ unsigned short f2bs(float f) {
    __hip_bfloat16 h = __float2bfloat16(f);
    return __builtin_bit_cast(unsigned short, h);
}
__device__ __forceinline__ float bs2f(ushort_t u) {
    u32 v = ((u32)u) << 16;
    return __builtin_bit_cast(float, v);
}
__device__ __forceinline__ u8 f2f8(float f) {
    return (u8)__hip_cvt_float_to_fp8(f, __HIP_SATFINITE, __HIP_E4M3);
}
__device__ __forceinline__ void gload16(const void* g, void* l) {
    __builtin_amdgcn_global_load_lds((const __attribute__((address_space(1))) u32*)g,
                                     (__attribute__((address_space(3))) u32*)l, 16, 0, 0);
}
__device__ __forceinline__ int xcd_swz(int bid, int nwg) {
    return (bid & 7) * (nwg >> 3) + (bid >> 3);
}

#define SBAR() __builtin_amdgcn_s_barrier()
#define LGKM0() do { asm volatile("s_waitcnt lgkmcnt(0)" ::: "memory"); \
                     __builtin_amdgcn_sched_barrier(0); } while (0)

// ============== 256x256 fp8 core: A global->registers, B via LDS (counted vmcnt) ==============
// NT GEMM fp8 e4m3: acc[8][4] (wave 128x64) += A[256][K] * B[256][K]^T, K%128==0, K/64>=2 even.
// 512 thr = 8 waves (2Mw x 4Nw). LDS 32 KiB (B-only, [buf][kh][256][32B]).
// Per K-tile(64): 2 phases. A-frags loaded 1 tile ahead, straight to VGPRs (16 dwordx2/lane,
// compiler-tracked waits). B staged via gload_lds; manual waits protect ONLY the B path:
// steady-state window between waits = 1 B-stage + 16 A-loads => vmcnt(17) at both wait points.
#define VMW17() asm volatile("s_waitcnt vmcnt(17)" ::: "memory")

#define STAGEB(BUF, KH, J) do {                                               \
    const int r_ = tid >> 1;                                                  \
    const int k_ = (J) * 64 + (KH) * 32 + (((tid & 1) ^ ((tid >> 3) & 1)) * 16); \
    gload16(Bm + (size_t)r_ * K + k_,                                         \
            (u8*)(&lds[BUF][KH][0][0]) + tid * 16);                           \
} while (0)

#define LDB(dst, BUF, KH) do {                                                \
    _Pragma("unroll")                                                         \
    for (int i_ = 0; i_ < 4; ++i_)                                            \
        dst[i_] = *(const long*)(&lds[BUF][KH][wnr + i_ * 16 + l16][f8off]);  \
} while (0)

// Load tile J's A-fragments into dst[8][2] (mf x kh), 8B each.
#define ALOAD(dst, J) do {                                                    \
    _Pragma("unroll")                                                         \
    for (int mf_ = 0; mf_ < 8; ++mf_) {                                       \
        dst[mf_][0] = *(const long*)(arow + (size_t)mf_ * 16 * K + (J) * 64);      \
        dst[mf_][1] = *(const long*)(arow + (size_t)mf_ * 16 * K + (J) * 64 + 32); \
    } } while (0)

#define MM32(av, bb, KH) do {                                                 \
    __builtin_amdgcn_s_setprio(1);                                            \
    _Pragma("unroll")                                                         \
    for (int mf_ = 0; mf_ < 8; ++mf_) {                                       \
        _Pragma("unroll")                                                     \
        for (int n_ = 0; n_ < 4; ++n_)                                        \
            acc[mf_][n_] = __builtin_amdgcn_mfma_f32_16x16x32_fp8_fp8(        \
                av[mf_][KH], bb[n_], acc[mf_][n_], 0, 0, 0);                  \
    }                                                                         \
    __builtin_amdgcn_s_setprio(0);                                            \
} while (0)

// One K-tile = 2 phases. ACUR used by MFMA; ANXT filled for tile JNXT. BUF literal 0/1.
#define KTILE_RA(ACUR, ANXT, BUF, JNXT) do {                                  \
    long b0[4];                                                               \
    /* phase 0 (kh0) */                                                       \
    LDB(b0, BUF, 0);                                                          \
    STAGEB(BUF ^ 1, 0, JNXT);                                                 \
    ALOAD(ANXT, JNXT);                                                        \
    SBAR(); LGKM0();                                                          \
    MM32(ACUR, b0, 0);                                                        \
    VMW17();                                                                  \
    SBAR();                                                                   \
    /* phase 1 (kh1) */                                                       \
    LDB(b0, BUF, 1);                                                          \
    STAGEB(BUF ^ 1, 1, JNXT);                                                 \
    SBAR(); LGKM0();                                                          \
    MM32(ACUR, b0, 1);                                                        \
    VMW17();                                                                  \
    SBAR();                                                                   \
} while (0)

typedef u8 ldsB_t[2][2][256][32];   // [buf][kh][row][32B] = 32 KiB

__device__ __forceinline__ void gemm256_f8ra(const u8* __restrict__ A,
                                             const u8* __restrict__ Bm,
                                             int K, ldsB_t& lds, fx4 acc[8][4])
{
    const int tid = threadIdx.x;
    const int lane = tid & 63;
    const int w = tid >> 6;
    const int l16 = lane & 15, lhi = lane >> 4;
    const int f8off = (((lhi >> 1) ^ ((l16 >> 2) & 1)) * 16) + (lhi & 1) * 8;
    const int wmr = (w >> 2) * 128;
    const int wnr = (w & 3) * 64;
    const int nkt = K >> 6;                           // even, >= 2
    const u8* arow = A + (size_t)(wmr + l16) * K + lhi * 8;

    long aA[8][2], aB[8][2];

    // prologue: B(0,kh0), B(0,kh1) staged; A(0) -> aA.  VMW(17) => B(0,kh0) complete.
    STAGEB(0, 0, 0);
    STAGEB(0, 1, 0);
    ALOAD(aA, 0);
    VMW17();
    SBAR();

    for (int jj = 0; jj < nkt; jj += 2) {
        const int jn1 = jj + 1;                               // < nkt always
        const int jn2 = (jj + 2 < nkt) ? jj + 2 : nkt - 1;    // clamped tail (dead restage/reload)
        KTILE_RA(aA, aB, 0, jn1);
        KTILE_RA(aB, aA, 1, jn2);
    }
    asm volatile("s_waitcnt vmcnt(0)" ::: "memory");  // drain before epilogue/exit
    SBAR();
}

#define EPI256_IDX() \
    const int lane = threadIdx.x & 63, w = threadIdx.x >> 6; \
    const int l16 = lane & 15, lhi = lane >> 4; \
    const int wmr = (w >> 2) * 128, wnr = (w & 3) * 64;

// ---------------- 128x128 2-phase bf16 core (k_sim only), T2-swizzled ----------------
__device__ __forceinline__ void mfma_core(const ushort_t* __restrict__ A,
                                          const ushort_t* __restrict__ Bm,
                                          int K, fx4 acc[4][4])
{
    __shared__ __align__(16) ushort_t As[128 * 32];
    __shared__ __align__(16) ushort_t Bs[128 * 32];
    const int tid = threadIdx.x;
    const int lane = tid & 63, wave = tid >> 6;
    const int l16 = lane & 15, lhi = lane >> 4;
    const int swz8 = (lhi ^ ((l16 >> 1) & 3)) * 8;
    const int wm = (wave >> 1) * 64, wn = (wave & 1) * 64;

    for (int k0 = 0; k0 < K; k0 += 32) {
        const int f0 = tid, f1 = tid + 256;
        gload16(A + (size_t)(f0 >> 2) * K + k0 + (((f0 & 3) ^ ((f0 >> 3) & 3)) * 8), As + f0 * 8);
        gload16(A + (size_t)(f1 >> 2) * K + k0 + (((f1 & 3) ^ ((f1 >> 3) & 3)) * 8), As + f1 * 8);
        gload16(Bm + (size_t)(f0 >> 2) * K + k0 + (((f0 & 3) ^ ((f0 >> 3) & 3)) * 8), Bs + f0 * 8);
        gload16(Bm + (size_t)(f1 >> 2) * K + k0 + (((f1 & 3) ^ ((f1 >> 3) & 3)) * 8), Bs + f1 * 8);
        __syncthreads();
        bfx8 af[4], bfr[4];
#pragma unroll
        for (int i = 0; i < 4; ++i)
            af[i] = *(const bfx8*)(As + (wm + i * 16 + l16) * 32 + swz8);
#pragma unroll
        for (int j = 0; j < 4; ++j)
            bfr[j] = *(const bfx8*)(Bs + (wn + j * 16 + l16) * 32 + swz8);
#pragma unroll
        for (int i = 0; i < 4; ++i)
#pragma unroll
            for (int j = 0; j < 4; ++j)
                acc[i][j] = __builtin_amdgcn_mfma_f32_16x16x32_bf16(af[i], bfr[j], acc[i][j], 0, 0, 0);
        __syncthreads();
    }
}

#define EPI_IDX() \
    const int lane = threadIdx.x & 63, wave = threadIdx.x >> 6; \
    const int l16 = lane & 15, lhi = lane >> 4; \
    const int wm = (wave >> 1) * 64, wn = (wave & 1) * 64;

// ---------------- casts ----------------
__global__ __launch_bounds__(256) void k_castw8(const float* __restrict__ s, u8* __restrict__ d,
                                                int n, float scale) {
    int i = (blockIdx.x * 256 + threadIdx.x) * 4;
    if (i >= n) return;
    float4 v = *(const float4*)(s + i);
    uchar4 o = { f2f8(v.x * scale), f2f8(v.y * scale), f2f8(v.z * scale), f2f8(v.w * scale) };
    *(uchar4*)(d + i) = o;
}

// x[b][c][n] -> xb bf16 [b][c][n], xb8 fp8x8 [b][c][n], xbT8 fp8x8 [b][n][c], xpart partial sums
__global__ __launch_bounds__(256) void k_cast_x(const float* __restrict__ x,
                                                ushort_t* __restrict__ xb, u8* __restrict__ xb8,
                                                u8* __restrict__ xbT8, float* __restrict__ xpart) {
    __shared__ float t[32][33];
    const int b = blockIdx.z, c0 = blockIdx.y * 32, n0 = blockIdx.x * 32;
    const int tn = threadIdx.x & 31, tc8 = threadIdx.x >> 5;
    const float* xp = x + ((size_t)b * C_ + c0) * N_ + n0;
#pragma unroll
    for (int p = 0; p < 4; ++p) {
        int cc = tc8 + p * 8;
        float v = xp[(size_t)cc * N_ + tn];
        t[cc][tn] = v;
        xb[((size_t)b * C_ + c0 + cc) * N_ + n0 + tn] = f2bs(v);
        xb8[((size_t)b * C_ + c0 + cc) * N_ + n0 + tn] = f2f8(v * 8.0f);
        float s = v;
#pragma unroll
        for (int o = 16; o; o >>= 1) s += __shfl_xor(s, o, 32);
        if (tn == 0) xpart[(size_t)blockIdx.x * B_ * C_ + (size_t)b * C_ + c0 + cc] = s;
    }
    __syncthreads();
#pragma unroll
    for (int p = 0; p < 4; ++p) {
        int nn = tc8 + p * 8;
        xbT8[((size_t)b * N_ + n0 + nn) * C_ + c0 + tn] = f2f8(t[tn][nn] * 8.0f);
    }
}

__global__ __launch_bounds__(256) void k_xsum2(const float* __restrict__ xpart, float* __restrict__ xsum) {
    const int c = blockIdx.x * 256 + threadIdx.x, b = blockIdx.y;
    float s = 0.f;
#pragma unroll
    for (int t = 0; t < 8; ++t) s += xpart[(size_t)t * B_ * C_ + (size_t)b * C_ + c];
    xsum[(size_t)b * C_ + c] = s;
}

// ---------------- exact-f32 score path ----------------
__global__ __launch_bounds__(256) void k_qsum(const float* __restrict__ xsum, const float* __restrict__ qw,
                                              const float* __restrict__ qb, float* __restrict__ qsum) {
    const int wave = threadIdx.x >> 6, lane = threadIdx.x & 63;
    const int row = blockIdx.x * 4 + wave;            // h*512+d, in [0, 2048)
    const int h = row >> 9, d = row & 511;
    const float* wr = qw + (size_t)row * C_;
    float acc[16];
#pragma unroll
    for (int bb = 0; bb < 16; ++bb) acc[bb] = 0.f;
    for (int it = 0; it < C_ / 64; ++it) {
        const int c = it * 64 + lane;
        const float w = wr[c];
#pragma unroll
        for (int bb = 0; bb < 16; ++bb) acc[bb] += xsum[(size_t)bb * C_ + c] * w;
    }
#pragma unroll
    for (int bb = 0; bb < 16; ++bb) {
        float s = acc[bb];
#pragma unroll
        for (int o = 32; o; o >>= 1) s += __shfl_xor(s, o, 64);
        if (lane == 0) qsum[(size_t)((bb << 2) | h) * D_ + d] = s + 256.0f * qb[row];
    }
}

__global__ __launch_bounds__(64) void k_const(const float* __restrict__ qsum, const float* __restrict__ kb,
                                              float* __restrict__ cst) {
    const int bh = blockIdx.x, h = bh & 3, lane = threadIdx.x;
    float s = 0.f;
    for (int d = lane; d < D_; d += 64) s += qsum[(size_t)bh * D_ + d] * kb[h * D_ + d];
#pragma unroll
    for (int o = 32; o; o >>= 1) s += __shfl_xor(s, o, 64);
    if (lane == 0) cst[bh] = s;
}

__global__ __launch_bounds__(256) void k_vecp(const float* __restrict__ qsum, const float* __restrict__ kw,
                                              float* __restrict__ partv) {
    const int ct = blockIdx.x, h = blockIdx.y, dsl = blockIdx.z;
    __shared__ float qs[16 * 128];
    for (int i = threadIdx.x; i < 16 * 128; i += 256) {
        int bb = i >> 7, dd = i & 127;
        qs[i] = qsum[(size_t)((bb << 2) | h) * D_ + dsl * 128 + dd];
    }
    __syncthreads();
    const int c = ct * 256 + threadIdx.x;
    const float* wp = kw + ((size_t)h * D_ + dsl * 128) * C_ + c;
    float acc[16];
#pragma unroll
    for (int bb = 0; bb < 16; ++bb) acc[bb] = 0.f;
    for (int dd = 0; dd < 128; ++dd) {
        const float w = wp[(size_t)dd * C_];
#pragma unroll
        for (int bb = 0; bb < 16; ++bb) acc[bb] += qs[bb * 128 + dd] * w;
    }
#pragma unroll
    for (int bb = 0; bb < 16; ++bb)
        partv[((size_t)dsl * 64 + ((bb << 2) | h)) * C_ + c] = acc[bb];
}

__global__ __launch_bounds__(256) void k_att(const float* __restrict__ x, const float* __restrict__ partv,
                                             float* __restrict__ part) {
    const int bh = blockIdx.x, sl = blockIdx.y, b = bh >> 2;
    __shared__ float vs[512];
    const int c0 = sl * 512;
    for (int i = threadIdx.x; i < 512; i += 256) {
        float v = 0.f;
#pragma unroll
        for (int dsl = 0; dsl < 4; ++dsl) v += partv[((size_t)dsl * 64 + bh) * C_ + c0 + i];
        vs[i] = v;
    }
    __syncthreads();
    float a = 0.f;
    const float* xp = x + ((size_t)b * C_ + c0) * N_ + threadIdx.x;
#pragma unroll 8
    for (int c = 0; c < 512; ++c) a += vs[c] * xp[(size_t)c * N_];
    part[((size_t)sl * 64 + bh) * N_ + threadIdx.x] = a;
}

__global__ __launch_bounds__(256) void k_score(const float* __restrict__ part, const float* __restrict__ cst,
                                               float* __restrict__ score, float* __restrict__ out0) {
    const int b = blockIdx.x, k = threadIdx.x;
    const float scale = 0.044194173824159216f;
    float a[4];
#pragma unroll
    for (int h = 0; h < 4; ++h) {
        const int bh = b * 4 + h;
        float s = cst[bh];
#pragma unroll
        for (int sl = 0; sl < 4; ++sl) s += part[((size_t)sl * 64 + bh) * N_ + k];
        a[h] = s * scale;
    }
    float mx = fmaxf(fmaxf(a[0], a[1]), fmaxf(a[2], a[3]));
    float e0 = expf(a[0] - mx), e1 = expf(a[1] - mx), e2 = expf(a[2] - mx), e3 = expf(a[3] - mx);
    float inv = 1.0f / (e0 + e1 + e2 + e3);
    float r[4] = { e0 * inv, e1 * inv, e2 * inv, e3 * inv };
#pragma unroll
    for (int h = 0; h < 4; ++h) {
        score[(size_t)(b * 4 + h) * N_ + k] = r[h];
        out0[(size_t)(b * 4 + h) * N_ + k] = r[h];
    }
}

// ---------------- fp8 reg-A MFMA GEMMs ----------------
// proj: M=(b,n)=4096, N=(qk,h,d)=4096, K=2048. A=xbT8(x8), B=qw8/kw8(x64) -> /512 + bias -> bf16.
__global__ __launch_bounds__(512, 2) void k_proj(const u8* __restrict__ xbT8,
                                                 const u8* __restrict__ qw8, const u8* __restrict__ kw8,
                                                 const float* __restrict__ qb, const float* __restrict__ kb,
                                                 ushort_t* __restrict__ QKbuf) {
    __shared__ __align__(16) ldsB_t lds;
    const int wg = xcd_swz(blockIdx.x, 256);
    const int quad = wg >> 2;
    const int mt = quad >> 2;                 // 0..15
    const int nt = (quad & 3) * 4 + (wg & 3); // 0..15
    const int c0 = nt * 256;
    const int qk = c0 >> 11;
    const int rem = c0 & 2047;                // h*512 + d0
    const u8* A  = xbT8 + (size_t)mt * 256 * C_;
    const u8* Bm = (qk ? kw8 : qw8) + (size_t)rem * C_;
    const float* bias  = (qk ? kb : qb) + rem;
    const int K = C_;

    fx4 acc[8][4];
#pragma unroll
    for (int i = 0; i < 8; ++i)
#pragma unroll
        for (int j = 0; j < 4; ++j) acc[i][j] = (fx4){0.f, 0.f, 0.f, 0.f};
    gemm256_f8ra(A, Bm, K, lds, acc);

    EPI256_IDX();
#pragma unroll
    for (int i = 0; i < 8; ++i)
#pragma unroll
        for (int n = 0; n < 4; ++n)
#pragma unroll
            for (int r = 0; r < 4; ++r) {
                const int gr = mt * 256 + wmr + i * 16 + lhi * 4 + r;
                const int bq = gr >> 8, nn = gr & 255;
                const int lc = wnr + n * 16 + l16;
                const int hh = (rem + lc) >> 9, dl = (rem + lc) & 511;
                const float v = acc[i][n][r] * (1.0f / 512.0f) + bias[lc];
                QKbuf[((((size_t)(qk * 16 + bq) * 4 + hh) * 256) + nn) * 512 + dl] = f2bs(v);
            }
}

// out: per h, M=e=2048, N=(b,n)=4096, K=2048. A=vw8(x64), B=Tt8(x16) -> /1024 + vb + score*x.
__global__ __launch_bounds__(512, 2) void k_out(const u8* __restrict__ vw8, const float* __restrict__ vb,
                                                const u8* __restrict__ Tt8, const float* __restrict__ score,
                                                const ushort_t* __restrict__ xb, float* __restrict__ out1) {
    __shared__ __align__(16) ldsB_t lds;
    const int wg = xcd_swz(blockIdx.x, 512);
    const int h = wg >> 7, l = wg & 127;
    const int quad = l >> 2;
    const int mt = quad >> 2;                 // 0..7
    const int nt = (quad & 3) * 4 + (l & 3);  // 0..15
    const u8* A  = vw8 + (size_t)h * C_ * C_ + (size_t)mt * 256 * C_;
    const u8* Bm = Tt8 + (size_t)h * 16 * N_ * C_ + (size_t)nt * 256 * C_;
    const int K = C_;

    fx4 acc[8][4];
#pragma unroll
    for (int i = 0; i < 8; ++i)
#pragma unroll
        for (int j = 0; j < 4; ++j) acc[i][j] = (fx4){0.f, 0.f, 0.f, 0.f};
    gemm256_f8ra(A, Bm, K, lds, acc);

    EPI256_IDX();
#pragma unroll
    for (int i = 0; i < 8; ++i)
#pragma unroll
        for (int n = 0; n < 4; ++n)
#pragma unroll
            for (int r = 0; r < 4; ++r) {
                const int e = mt * 256 + wmr + i * 16 + lhi * 4 + r;
                const int col = nt * 256 + wnr + n * 16 + l16;
                const int b = col >> 8, nn = col & 255;
                float v = acc[i][n][r] * (1.0f / 1024.0f) + vb[h * C_ + e]
                        + score[(size_t)(b * 4 + h) * N_ + nn] * bs2f(xb[((size_t)b * C_ + e) * N_ + nn]);
                out1[((size_t)(b * 4 + h) * C_ + e) * N_ + nn] = v;
            }
}

// T: per b, M=(h,q)=1024, N=c=2048, K=256. A=Pb8(x256), B=xb8(x8) -> acc/2048, store fp8 x16.
__global__ __launch_bounds__(512, 2) void k_T8(const u8* __restrict__ Pb8, const u8* __restrict__ xb8,
                                               u8* __restrict__ Tt8) {
    __shared__ __align__(16) ldsB_t lds;
    const int wg = xcd_swz(blockIdx.x, 512);
    const int b = wg >> 5, l = wg & 31;       // 16 b x (4 mt x 8 nt)
    const int mt = l >> 3, nt = l & 7;
    const u8* A  = Pb8 + ((size_t)b * 1024 + mt * 256) * 256;
    const u8* Bm = xb8 + ((size_t)b * 2048 + nt * 256) * 256;
    const int K = N_;

    fx4 acc[8][4];
#pragma unroll
    for (int i = 0; i < 8; ++i)
#pragma unroll
        for (int j = 0; j < 4; ++j) acc[i][j] = (fx4){0.f, 0.f, 0.f, 0.f};
    gemm256_f8ra(A, Bm, K, lds, acc);

    EPI256_IDX();
#pragma unroll
    for (int i = 0; i < 8; ++i)
#pragma unroll
        for (int n = 0; n < 4; ++n)
#pragma unroll
            for (int r = 0; r < 4; ++r) {
                const int rowm = mt * 256 + wmr + i * 16 + lhi * 4 + r;
                const int h = rowm >> 8, q = rowm & 255;
                const int c = nt * 256 + wnr + n * 16 + l16;
                // unscale 1/(256*8), restore T, then store T*16 as fp8:
                Tt8[(((size_t)h * 16 + b) * 256 + q) * 2048 + c] = f2f8(acc[i][n][r] * 0.0078125f);
            }
}

// sim: per bh, 128x128 tiles, K=512 (bf16 2-phase core). simf f32.
__global__ __launch_bounds__(256) void k_sim(const ushort_t* __restrict__ QKbuf, float* __restrict__ simf) {
    const int wg = blockIdx.x;
    const int bh = wg >> 2, mt = (wg >> 1) & 1, ntl = wg & 1;
    const ushort_t* Qr = QKbuf;
    const ushort_t* Kr = QKbuf + (size_t)16 * 4 * 256 * 512;
    const ushort_t* A = Qr + ((size_t)bh * 256 + mt * 128) * 512;
    const ushort_t* Bm = Kr + ((size_t)bh * 256 + ntl * 128) * 512;

    fx4 acc[4][4];
#pragma unroll
    for (int i = 0; i < 4; ++i)
#pragma unroll
        for (int j = 0; j < 4; ++j) acc[i][j] = (fx4){0.f, 0.f, 0.f, 0.f};
    mfma_core(A, Bm, D_, acc);

    EPI_IDX();
    const float scale = 0.044194173824159216f;
#pragma unroll
    for (int i = 0; i < 4; ++i)
#pragma unroll
        for (int j = 0; j < 4; ++j)
#pragma unroll
            for (int r = 0; r < 4; ++r) {
                const int q = mt * 128 + wm + i * 16 + lhi * 4 + r;
                const int k = ntl * 128 + wn + j * 16 + l16;
                simf[(size_t)bh * N_ * N_ + (size_t)q * N_ + k] = acc[i][j][r] * scale;
            }
}

__global__ __launch_bounds__(64) void k_softP(const float* __restrict__ simf, u8* __restrict__ Pb8) {
    const size_t row = blockIdx.x;
    const float* p = simf + row * N_;
    u8* o = Pb8 + row * N_;
    const int t = threadIdx.x;
    float v0 = p[t], v1 = p[t + 64], v2 = p[t + 128], v3 = p[t + 192];
    float mx = fmaxf(fmaxf(v0, v1), fmaxf(v2, v3));
#pragma unroll
    for (int off = 32; off; off >>= 1) mx = fmaxf(mx, __shfl_xor(mx, off, 64));
    float e0 = expf(v0 - mx), e1 = expf(v1 - mx), e2 = expf(v2 - mx), e3 = expf(v3 - mx);
    float s = e0 + e1 + e2 + e3;
#pragma unroll
    for (int off = 32; off; off >>= 1) s += __shfl_xor(s, off, 64);
    const float inv = 256.0f / s;     // store P * 256 as fp8
    o[t] = f2f8(e0 * inv); o[t + 64] = f2f8(e1 * inv);
    o[t + 128] = f2f8(e2 * inv); o[t + 192] = f2f8(e3 * inv);
}

extern "C" void kernel_launch(void* const* d_in, const int* in_sizes, int n_in,
                              void* d_out, int out_size, void* d_ws, size_t ws_size,
                              hipStream_t stream)
{
    const float* x  = (const float*)d_in[0];
    const float* qw = (const float*)d_in[1];
    const float* qb = (const float*)d_in[2];
    const float* kw = (const float*)d_in[3];
    const float* kb = (const float*)d_in[4];
    const float* vw = (const float*)d_in[5];
    const float* vb = (const float*)d_in[6];

    float* out0 = (float*)d_out;
    float* out1 = out0 + (size_t)B_ * HEADS_ * N_;

    char* w = (char*)d_ws;
    u8*       vw8  = (u8*)w;        w += (size_t)4 * C_ * C_;              // 16.8MB
    u8*       qw8  = (u8*)w;        w += (size_t)4 * D_ * C_;              // 4.2MB
    u8*       kw8  = (u8*)w;        w += (size_t)4 * D_ * C_;              // 4.2MB
    ushort_t* xb   = (ushort_t*)w;  w += (size_t)B_ * C_ * N_ * 2;         // 16.8MB (bf16, gating)
    u8*       xb8  = (u8*)w;        w += (size_t)B_ * C_ * N_;             // 8.4MB
    u8*       xbT8 = (u8*)w;        w += (size_t)B_ * N_ * C_;             // 8.4MB
    ushort_t* QKbuf= (ushort_t*)w;  w += (size_t)2 * 16 * 4 * 256 * 512 * 2; // 33.6MB bf16
    u8*       Pb8  = (u8*)w;        w += (size_t)64 * N_ * N_;             // 4.2MB
    float*    simf = (float*)w;     w += (size_t)64 * N_ * N_ * 4;         // 16.8MB
    u8*       Tt8  = (u8*)w;        w += (size_t)64 * N_ * C_;             // 33.6MB
    float*    xpart= (float*)w;     w += (size_t)8 * B_ * C_ * 4;          // 1MB
    float*    xsum = (float*)w;     w += (size_t)B_ * C_ * 4;
    float*    qsum = (float*)w;     w += (size_t)64 * D_ * 4;
    float*    cst  = (float*)w;     w += 1024;
    float*    partv= (float*)w;     w += (size_t)4 * 64 * C_ * 4;          // 2.1MB
    float*    part = (float*)w;     w += (size_t)4 * 64 * N_ * 4;
    float*    score= (float*)w;     w += (size_t)64 * N_ * 4;

    // casts (weights x64 -> fp8; x -> bf16 + fp8 x8 + transposed fp8 x8)
    k_castw8<<<dim3(4 * D_ * C_ / 4 / 256), 256, 0, stream>>>(qw, qw8, 4 * D_ * C_, 64.0f);
    k_castw8<<<dim3(4 * D_ * C_ / 4 / 256), 256, 0, stream>>>(kw, kw8, 4 * D_ * C_, 64.0f);
    k_castw8<<<dim3(4 * C_ * C_ / 4 / 256), 256, 0, stream>>>(vw, vw8, 4 * C_ * C_, 64.0f);
    k_cast_x<<<dim3(8, 64, 16), 256, 0, stream>>>(x, xb, xb8, xbT8, xpart);

    // exact-f32 score path
    k_xsum2<<<dim3(8, 16), 256, 0, stream>>>(xpart, xsum);
    k_qsum <<<dim3(512), 256, 0, stream>>>(xsum, qw, qb, qsum);
    k_const<<<dim3(64), 64, 0, stream>>>(qsum, kb, cst);
    k_vecp <<<dim3(8, 4, 4), 256, 0, stream>>>(qsum, kw, partv);
    k_att  <<<dim3(64, 4), 256, 0, stream>>>(x, partv, part);
    k_score<<<dim3(16), 256, 0, stream>>>(part, cst, score, out0);

    // MFMA pipeline
    k_proj <<<dim3(256), 512, 0, stream>>>(xbT8, qw8, kw8, qb, kb, QKbuf);
    k_sim  <<<dim3(256), 256, 0, stream>>>(QKbuf, simf);
    k_softP<<<dim3(64 * N_), 64, 0, stream>>>(simf, Pb8);
    k_T8   <<<dim3(512), 512, 0, stream>>>(Pb8, xb8, Tt8);
    k_out  <<<dim3(512), 512, 0, stream>>>(vw8, vb, Tt8, score, xb, out1);
}

// Round 11
// 390.636 us; speedup vs baseline: 1.7138x; 1.7138x over previous
//
#include <hip/hip_runtime.h>
#include <hip/hip_bf16.h>
#include <hip/hip_fp8.h>

#define B_ 16
#define C_ 2048
#define N_ 256
#define HEADS_ 4
#define D_ 512

typedef unsigned int u32;
typedef unsigned char u8;
typedef unsigned long long u64;
typedef unsigned short ushort_t;
typedef __attribute__((ext_vector_type(8))) short bfx8;
typedef __attribute__((ext_vector_type(4))) float fx4;
typedef __attribute__((ext_vector_type(2))) long longx2;

__device__ __forceinline__ unsigned short f2bs(float f) {
    __hip_bfloat16 h = __float2bfloat16(f);
    return __builtin_bit_cast(unsigned short, h);
}
__device__ __forceinline__ float bs2f(ushort_t u) {
    u32 v = ((u32)u) << 16;
    return __builtin_bit_cast(float, v);
}
__device__ __forceinline__ u8 f2f8(float f) {
    return (u8)__hip_cvt_float_to_fp8(f, __HIP_SATFINITE, __HIP_E4M3);
}
__device__ __forceinline__ u32 pk4(float4 v, float s) {
    return (u32)f2f8(v.x * s) | ((u32)f2f8(v.y * s) << 8) |
           ((u32)f2f8(v.z * s) << 16) | ((u32)f2f8(v.w * s) << 24);
}
__device__ __forceinline__ void gload16(const void* g, void* l) {
    __builtin_amdgcn_global_load_lds((const __attribute__((address_space(1))) u32*)g,
                                     (__attribute__((address_space(3))) u32*)l, 16, 0, 0);
}
__device__ __forceinline__ int xcd_swz(int bid, int nwg) {
    return (bid & 7) * (nwg >> 3) + (bid >> 3);
}

#define SBAR() __builtin_amdgcn_s_barrier()
#define LGKM0() do { asm volatile("s_waitcnt lgkmcnt(0)" ::: "memory"); \
                     __builtin_amdgcn_sched_barrier(0); } while (0)

// ============ 256x256 fp8 core: packed-A global->regs (coalesced), B via LDS ============
// NT GEMM fp8 e4m3: acc[8][4] (wave 128x64) += A[256][K] * B[256][K]^T, K%128==0.
// 512 thr = 8 waves (2Mw x 4Nw). LDS 32 KiB (B-only dbuf). 2 phases per K-tile(64).
// A is FRAGMENT-PACKED: chunk(j,half,mf,lane) = 16B {kh0: A[row][j*64+lhi*8..], kh1: +32}
// with row = half*128+mf*16+l16, lane = lhi*16+l16. ALOADPK = 8x dwordx4, 1KB contiguous
// per wave per instr (fixes round-10's 64-line scatter). Issue order per tile:
// [S(kh0), 8xA, S(kh1)] -> both manual waits = vmcnt(9) (B-region readiness; A readiness
// is compiler-counted, issued 2 phases ahead).
#define VMW9() asm volatile("s_waitcnt vmcnt(9)" ::: "memory")

#define STAGEB(BUF, KH, J) do {                                               \
    const int r_ = tid >> 1;                                                  \
    const int k_ = (J) * 64 + (KH) * 32 + (((tid & 1) ^ ((tid >> 3) & 1)) * 16); \
    gload16(Bm + (size_t)r_ * K + k_,                                         \
            (u8*)(&lds[BUF][KH][0][0]) + tid * 16);                           \
} while (0)

#define LDB(dst, BUF, KH) do {                                                \
    _Pragma("unroll")                                                         \
    for (int i_ = 0; i_ < 4; ++i_)                                            \
        dst[i_] = *(const long*)(&lds[BUF][KH][wnr + i_ * 16 + l16][f8off]);  \
} while (0)

#define ALOADPK(dst, J) do {                                                  \
    _Pragma("unroll")                                                         \
    for (int mf_ = 0; mf_ < 8; ++mf_)                                         \
        dst[mf_] = *(const longx2*)(Ap + ((size_t)((J) * 16 + halfsel + mf_) * 64 + lane) * 16); \
} while (0)

#define MM32PK(av, bb, KH) do {                                               \
    __builtin_amdgcn_s_setprio(1);                                            \
    _Pragma("unroll")                                                         \
    for (int mf_ = 0; mf_ < 8; ++mf_) {                                       \
        _Pragma("unroll")                                                     \
        for (int n_ = 0; n_ < 4; ++n_)                                        \
            acc[mf_][n_] = __builtin_amdgcn_mfma_f32_16x16x32_fp8_fp8(        \
                av[mf_][KH], bb[n_], acc[mf_][n_], 0, 0, 0);                  \
    }                                                                         \
    __builtin_amdgcn_s_setprio(0);                                            \
} while (0)

// One K-tile = 2 phases. ACUR consumed; ANXT loaded for tile JNXT. BUF literal 0/1.
#define KTILE_PK(ACUR, ANXT, BUF, JNXT) do {                                  \
    long b0[4];                                                               \
    /* phase 0 (kh0) */                                                       \
    LDB(b0, BUF, 0);                                                          \
    STAGEB(BUF ^ 1, 0, JNXT);                                                 \
    ALOADPK(ANXT, JNXT);                                                      \
    SBAR(); LGKM0();                                                          \
    MM32PK(ACUR, b0, 0);                                                      \
    VMW9();                                                                   \
    SBAR();                                                                   \
    /* phase 1 (kh1) */                                                       \
    LDB(b0, BUF, 1);                                                          \
    STAGEB(BUF ^ 1, 1, JNXT);                                                 \
    SBAR(); LGKM0();                                                          \
    MM32PK(ACUR, b0, 1);                                                      \
    VMW9();                                                                   \
    SBAR();                                                                   \
} while (0)

typedef u8 ldsB_t[2][2][256][32];   // [buf][kh][row][32B] = 32 KiB

__device__ __forceinline__ void gemm256_pk(const u8* __restrict__ Ap,
                                           const u8* __restrict__ Bm,
                                           int K, ldsB_t& lds, fx4 acc[8][4])
{
    const int tid = threadIdx.x;
    const int lane = tid & 63;
    const int w = tid >> 6;
    const int l16 = lane & 15, lhi = lane >> 4;
    const int f8off = (((lhi >> 1) ^ ((l16 >> 2) & 1)) * 16) + (lhi & 1) * 8;
    const int wnr = (w & 3) * 64;
    const int halfsel = (w >> 2) * 8;
    const int nkt = K >> 6;                           // even, >= 2

    longx2 aA[8], aB[8];

    // prologue: B(t0,kh0), B(t0,kh1) staged; A(t0) -> aA.
    STAGEB(0, 0, 0);
    STAGEB(0, 1, 0);
    ALOADPK(aA, 0);
    VMW9();
    SBAR();

    for (int jj = 0; jj < nkt; jj += 2) {
        const int jn1 = jj + 1;                               // < nkt always
        const int jn2 = (jj + 2 < nkt) ? jj + 2 : nkt - 1;    // clamped tail (dead reload)
        KTILE_PK(aA, aB, 0, jn1);
        KTILE_PK(aB, aA, 1, jn2);
    }
    asm volatile("s_waitcnt vmcnt(0)" ::: "memory");  // drain before epilogue/exit
    SBAR();
}

#define EPI256_IDX() \
    const int lane = threadIdx.x & 63, w = threadIdx.x >> 6; \
    const int l16 = lane & 15, lhi = lane >> 4; \
    const int wmr = (w >> 2) * 128, wnr = (w & 3) * 64;

// ---------------- 128x128 2-phase bf16 core (k_sim only), T2-swizzled ----------------
__device__ __forceinline__ void mfma_core(const ushort_t* __restrict__ A,
                                          const ushort_t* __restrict__ Bm,
                                          int K, fx4 acc[4][4])
{
    __shared__ __align__(16) ushort_t As[128 * 32];
    __shared__ __align__(16) ushort_t Bs[128 * 32];
    const int tid = threadIdx.x;
    const int lane = tid & 63, wave = tid >> 6;
    const int l16 = lane & 15, lhi = lane >> 4;
    const int swz8 = (lhi ^ ((l16 >> 1) & 3)) * 8;
    const int wm = (wave >> 1) * 64, wn = (wave & 1) * 64;

    for (int k0 = 0; k0 < K; k0 += 32) {
        const int f0 = tid, f1 = tid + 256;
        gload16(A + (size_t)(f0 >> 2) * K + k0 + (((f0 & 3) ^ ((f0 >> 3) & 3)) * 8), As + f0 * 8);
        gload16(A + (size_t)(f1 >> 2) * K + k0 + (((f1 & 3) ^ ((f1 >> 3) & 3)) * 8), As + f1 * 8);
        gload16(Bm + (size_t)(f0 >> 2) * K + k0 + (((f0 & 3) ^ ((f0 >> 3) & 3)) * 8), Bs + f0 * 8);
        gload16(Bm + (size_t)(f1 >> 2) * K + k0 + (((f1 & 3) ^ ((f1 >> 3) & 3)) * 8), Bs + f1 * 8);
        __syncthreads();
        bfx8 af[4], bfr[4];
#pragma unroll
        for (int i = 0; i < 4; ++i)
            af[i] = *(const bfx8*)(As + (wm + i * 16 + l16) * 32 + swz8);
#pragma unroll
        for (int j = 0; j < 4; ++j)
            bfr[j] = *(const bfx8*)(Bs + (wn + j * 16 + l16) * 32 + swz8);
#pragma unroll
        for (int i = 0; i < 4; ++i)
#pragma unroll
            for (int j = 0; j < 4; ++j)
                acc[i][j] = __builtin_amdgcn_mfma_f32_16x16x32_bf16(af[i], bfr[j], acc[i][j], 0, 0, 0);
        __syncthreads();
    }
}

#define EPI_IDX() \
    const int lane = threadIdx.x & 63, wave = threadIdx.x >> 6; \
    const int l16 = lane & 15, lhi = lane >> 4; \
    const int wm = (wave >> 1) * 64, wn = (wave & 1) * 64;

// ---------------- casts / packs ----------------
__global__ __launch_bounds__(256) void k_castw8(const float* __restrict__ s, u8* __restrict__ d,
                                                int n, float scale) {
    int i = (blockIdx.x * 256 + threadIdx.x) * 4;
    if (i >= n) return;
    float4 v = *(const float4*)(s + i);
    uchar4 o = { f2f8(v.x * scale), f2f8(v.y * scale), f2f8(v.z * scale), f2f8(v.w * scale) };
    *(uchar4*)(d + i) = o;
}

// vw f32 [h][e][c] -> fragment-packed fp8 (x64). panel = h*8 + (e>>8); 32 j-slabs.
__global__ __launch_bounds__(256) void k_packvw(const float* __restrict__ vw, u8* __restrict__ vw8pk) {
    const int j = blockIdx.x;            // 0..31
    const int panel = blockIdx.y;        // 0..31
    const int h = panel >> 3;
    const int ebase = (panel & 7) * 256;
#pragma unroll
    for (int c4 = 0; c4 < 4; ++c4) {
        const int chunk = threadIdx.x + c4 * 256;           // 0..1023
        const int half = chunk >> 9, mf = (chunk >> 6) & 7, lane = chunk & 63;
        const int lhi = lane >> 4, l16 = lane & 15;
        const int e = ebase + half * 128 + mf * 16 + l16;
        const float* sp = vw + ((size_t)h * C_ + e) * C_ + j * 64 + lhi * 8;
        uint4 o;
        o.x = pk4(*(const float4*)(sp), 64.0f);
        o.y = pk4(*(const float4*)(sp + 4), 64.0f);
        o.z = pk4(*(const float4*)(sp + 32), 64.0f);
        o.w = pk4(*(const float4*)(sp + 36), 64.0f);
        *(uint4*)(vw8pk + (size_t)panel * 256 * C_ +
                  (((size_t)j * 16 + half * 8 + mf) * 64 + lane) * 16) = o;
    }
}

// x[b][c][n] -> xb bf16, xb8 fp8 (x8) linear, xbT8pk fragment-packed (panel=b, row=n, K=c),
// xpart partial n-sums.
__global__ __launch_bounds__(256) void k_cast_x(const float* __restrict__ x,
                                                ushort_t* __restrict__ xb, u8* __restrict__ xb8,
                                                u8* __restrict__ xbT8pk, float* __restrict__ xpart) {
    __shared__ float t[32][33];
    const int b = blockIdx.z, c0 = blockIdx.y * 32, n0 = blockIdx.x * 32;
    const int tn = threadIdx.x & 31, tc8 = threadIdx.x >> 5;
    const float* xp = x + ((size_t)b * C_ + c0) * N_ + n0;
#pragma unroll
    for (int p = 0; p < 4; ++p) {
        int cc = tc8 + p * 8;
        float v = xp[(size_t)cc * N_ + tn];
        t[cc][tn] = v;
        xb[((size_t)b * C_ + c0 + cc) * N_ + n0 + tn] = f2bs(v);
        xb8[((size_t)b * C_ + c0 + cc) * N_ + n0 + tn] = f2f8(v * 8.0f);
        float s = v;
#pragma unroll
        for (int o = 16; o; o >>= 1) s += __shfl_xor(s, o, 32);
        if (tn == 0) xpart[(size_t)blockIdx.x * B_ * C_ + (size_t)b * C_ + c0 + cc] = s;
    }
    __syncthreads();
    const int jX = c0 >> 6, khX = (c0 >> 5) & 1;   // fixed per block (c0 is 32-aligned)
    const int lhiX = tn >> 3, bofs = tn & 7;
#pragma unroll
    for (int p = 0; p < 4; ++p) {
        int nn = tc8 + p * 8;
        int n = n0 + nn;
        int half = n >> 7, mf = (n >> 4) & 7, l16 = n & 15;
        xbT8pk[(size_t)b * 256 * C_ +
               (((size_t)jX * 16 + half * 8 + mf) * 64 + lhiX * 16 + l16) * 16 + khX * 8 + bofs]
            = f2f8(t[tn][nn] * 8.0f);
    }
}

__global__ __launch_bounds__(256) void k_xsum2(const float* __restrict__ xpart, float* __restrict__ xsum) {
    const int c = blockIdx.x * 256 + threadIdx.x, b = blockIdx.y;
    float s = 0.f;
#pragma unroll
    for (int t = 0; t < 8; ++t) s += xpart[(size_t)t * B_ * C_ + (size_t)b * C_ + c];
    xsum[(size_t)b * C_ + c] = s;
}

// ---------------- exact-f32 score path ----------------
__global__ __launch_bounds__(256) void k_qsum(const float* __restrict__ xsum, const float* __restrict__ qw,
                                              const float* __restrict__ qb, float* __restrict__ qsum) {
    const int wave = threadIdx.x >> 6, lane = threadIdx.x & 63;
    const int row = blockIdx.x * 4 + wave;            // h*512+d, in [0, 2048)
    const int h = row >> 9, d = row & 511;
    const float* wr = qw + (size_t)row * C_;
    float acc[16];
#pragma unroll
    for (int bb = 0; bb < 16; ++bb) acc[bb] = 0.f;
    for (int it = 0; it < C_ / 64; ++it) {
        const int c = it * 64 + lane;
        const float w = wr[c];
#pragma unroll
        for (int bb = 0; bb < 16; ++bb) acc[bb] += xsum[(size_t)bb * C_ + c] * w;
    }
#pragma unroll
    for (int bb = 0; bb < 16; ++bb) {
        float s = acc[bb];
#pragma unroll
        for (int o = 32; o; o >>= 1) s += __shfl_xor(s, o, 64);
        if (lane == 0) qsum[(size_t)((bb << 2) | h) * D_ + d] = s + 256.0f * qb[row];
    }
}

__global__ __launch_bounds__(64) void k_const(const float* __restrict__ qsum, const float* __restrict__ kb,
                                              float* __restrict__ cst) {
    const int bh = blockIdx.x, h = bh & 3, lane = threadIdx.x;
    float s = 0.f;
    for (int d = lane; d < D_; d += 64) s += qsum[(size_t)bh * D_ + d] * kb[h * D_ + d];
#pragma unroll
    for (int o = 32; o; o >>= 1) s += __shfl_xor(s, o, 64);
    if (lane == 0) cst[bh] = s;
}

__global__ __launch_bounds__(256) void k_vecp(const float* __restrict__ qsum, const float* __restrict__ kw,
                                              float* __restrict__ partv) {
    const int ct = blockIdx.x, h = blockIdx.y, dsl = blockIdx.z;
    __shared__ float qs[16 * 128];
    for (int i = threadIdx.x; i < 16 * 128; i += 256) {
        int bb = i >> 7, dd = i & 127;
        qs[i] = qsum[(size_t)((bb << 2) | h) * D_ + dsl * 128 + dd];
    }
    __syncthreads();
    const int c = ct * 256 + threadIdx.x;
    const float* wp = kw + ((size_t)h * D_ + dsl * 128) * C_ + c;
    float acc[16];
#pragma unroll
    for (int bb = 0; bb < 16; ++bb) acc[bb] = 0.f;
    for (int dd = 0; dd < 128; ++dd) {
        const float w = wp[(size_t)dd * C_];
#pragma unroll
        for (int bb = 0; bb < 16; ++bb) acc[bb] += qs[bb * 128 + dd] * w;
    }
#pragma unroll
    for (int bb = 0; bb < 16; ++bb)
        partv[((size_t)dsl * 64 + ((bb << 2) | h)) * C_ + c] = acc[bb];
}

__global__ __launch_bounds__(256) void k_att(const float* __restrict__ x, const float* __restrict__ partv,
                                             float* __restrict__ part) {
    const int bh = blockIdx.x, sl = blockIdx.y, b = bh >> 2;
    __shared__ float vs[512];
    const int c0 = sl * 512;
    for (int i = threadIdx.x; i < 512; i += 256) {
        float v = 0.f;
#pragma unroll
        for (int dsl = 0; dsl < 4; ++dsl) v += partv[((size_t)dsl * 64 + bh) * C_ + c0 + i];
        vs[i] = v;
    }
    __syncthreads();
    float a = 0.f;
    const float* xp = x + ((size_t)b * C_ + c0) * N_ + threadIdx.x;
#pragma unroll 8
    for (int c = 0; c < 512; ++c) a += vs[c] * xp[(size_t)c * N_];
    part[((size_t)sl * 64 + bh) * N_ + threadIdx.x] = a;
}

__global__ __launch_bounds__(256) void k_score(const float* __restrict__ part, const float* __restrict__ cst,
                                               float* __restrict__ score, float* __restrict__ out0) {
    const int b = blockIdx.x, k = threadIdx.x;
    const float scale = 0.044194173824159216f;
    float a[4];
#pragma unroll
    for (int h = 0; h < 4; ++h) {
        const int bh = b * 4 + h;
        float s = cst[bh];
#pragma unroll
        for (int sl = 0; sl < 4; ++sl) s += part[((size_t)sl * 64 + bh) * N_ + k];
        a[h] = s * scale;
    }
    float mx = fmaxf(fmaxf(a[0], a[1]), fmaxf(a[2], a[3]));
    float e0 = expf(a[0] - mx), e1 = expf(a[1] - mx), e2 = expf(a[2] - mx), e3 = expf(a[3] - mx);
    float inv = 1.0f / (e0 + e1 + e2 + e3);
    float r[4] = { e0 * inv, e1 * inv, e2 * inv, e3 * inv };
#pragma unroll
    for (int h = 0; h < 4; ++h) {
        score[(size_t)(b * 4 + h) * N_ + k] = r[h];
        out0[(size_t)(b * 4 + h) * N_ + k] = r[h];
    }
}

// ---------------- fp8 packed-A MFMA GEMMs ----------------
// proj: M=(b,n)=4096, N=(qk,h,d)=4096, K=2048. A=xbT8pk(x8), B=qw8/kw8(x64) -> /512 + bias.
__global__ __launch_bounds__(512, 2) void k_proj(const u8* __restrict__ xbT8pk,
                                                 const u8* __restrict__ qw8, const u8* __restrict__ kw8,
                                                 const float* __restrict__ qb, const float* __restrict__ kb,
                                                 ushort_t* __restrict__ QKbuf) {
    __shared__ __align__(16) ldsB_t lds;
    const int wg = xcd_swz(blockIdx.x, 256);
    const int quad = wg >> 2;
    const int mt = quad >> 2;                 // 0..15
    const int nt = (quad & 3) * 4 + (wg & 3); // 0..15
    const int c0 = nt * 256;
    const int qk = c0 >> 11;
    const int rem = c0 & 2047;                // h*512 + d0
    const u8* Ap = xbT8pk + (size_t)mt * 256 * C_;
    const u8* Bm = (qk ? kw8 : qw8) + (size_t)rem * C_;
    const float* bias  = (qk ? kb : qb) + rem;
    const int K = C_;

    fx4 acc[8][4];
#pragma unroll
    for (int i = 0; i < 8; ++i)
#pragma unroll
        for (int j = 0; j < 4; ++j) acc[i][j] = (fx4){0.f, 0.f, 0.f, 0.f};
    gemm256_pk(Ap, Bm, K, lds, acc);

    EPI256_IDX();
#pragma unroll
    for (int i = 0; i < 8; ++i)
#pragma unroll
        for (int n = 0; n < 4; ++n)
#pragma unroll
            for (int r = 0; r < 4; ++r) {
                const int gr = mt * 256 + wmr + i * 16 + lhi * 4 + r;
                const int bq = gr >> 8, nn = gr & 255;
                const int lc = wnr + n * 16 + l16;
                const int hh = (rem + lc) >> 9, dl = (rem + lc) & 511;
                const float v = acc[i][n][r] * (1.0f / 512.0f) + bias[lc];
                QKbuf[((((size_t)(qk * 16 + bq) * 4 + hh) * 256) + nn) * 512 + dl] = f2bs(v);
            }
}

// out: per h, M=e=2048, N=(b,n)=4096, K=2048. A=vw8pk(x64), B=Tt8(x16) -> /1024 + vb + score*x.
__global__ __launch_bounds__(512, 2) void k_out(const u8* __restrict__ vw8pk, const float* __restrict__ vb,
                                                const u8* __restrict__ Tt8, const float* __restrict__ score,
                                                const ushort_t* __restrict__ xb, float* __restrict__ out1) {
    __shared__ __align__(16) ldsB_t lds;
    const int wg = xcd_swz(blockIdx.x, 512);
    const int h = wg >> 7, l = wg & 127;
    const int quad = l >> 2;
    const int mt = quad >> 2;                 // 0..7
    const int nt = (quad & 3) * 4 + (l & 3);  // 0..15
    const u8* Ap = vw8pk + (size_t)h * C_ * C_ + (size_t)mt * 256 * C_;
    const u8* Bm = Tt8 + (size_t)h * 16 * N_ * C_ + (size_t)nt * 256 * C_;
    const int K = C_;

    fx4 acc[8][4];
#pragma unroll
    for (int i = 0; i < 8; ++i)
#pragma unroll
        for (int j = 0; j < 4; ++j) acc[i][j] = (fx4){0.f, 0.f, 0.f, 0.f};
    gemm256_pk(Ap, Bm, K, lds, acc);

    EPI256_IDX();
#pragma unroll
    for (int i = 0; i < 8; ++i)
#pragma unroll
        for (int n = 0; n < 4; ++n)
#pragma unroll
            for (int r = 0; r < 4; ++r) {
                const int e = mt * 256 + wmr + i * 16 + lhi * 4 + r;
                const int col = nt * 256 + wnr + n * 16 + l16;
                const int b = col >> 8, nn = col & 255;
                float v = acc[i][n][r] * (1.0f / 1024.0f) + vb[h * C_ + e]
                        + score[(size_t)(b * 4 + h) * N_ + nn] * bs2f(xb[((size_t)b * C_ + e) * N_ + nn]);
                out1[((size_t)(b * 4 + h) * C_ + e) * N_ + nn] = v;
            }
}

// T: per b, M=(h,q)=1024, N=c=2048, K=256. A=Pb8pk(x256), B=xb8(x8) -> /2048, store fp8 x16.
__global__ __launch_bounds__(512, 2) void k_T8(const u8* __restrict__ Pb8pk, const u8* __restrict__ xb8,
                                               u8* __restrict__ Tt8) {
    __shared__ __align__(16) ldsB_t lds;
    const int wg = xcd_swz(blockIdx.x, 512);
    const int b = wg >> 5, l = wg & 31;       // 16 b x (4 mt x 8 nt)
    const int mt = l >> 3, nt = l & 7;
    const u8* Ap = Pb8pk + ((size_t)b * 1024 + mt * 256) * 256;
    const u8* Bm = xb8 + ((size_t)b * 2048 + nt * 256) * 256;
    const int K = N_;

    fx4 acc[8][4];
#pragma unroll
    for (int i = 0; i < 8; ++i)
#pragma unroll
        for (int j = 0; j < 4; ++j) acc[i][j] = (fx4){0.f, 0.f, 0.f, 0.f};
    gemm256_pk(Ap, Bm, K, lds, acc);

    EPI256_IDX();
#pragma unroll
    for (int i = 0; i < 8; ++i)
#pragma unroll
        for (int n = 0; n < 4; ++n)
#pragma unroll
            for (int r = 0; r < 4; ++r) {
                const int rowm = mt * 256 + wmr + i * 16 + lhi * 4 + r;
                const int h = rowm >> 8, q = rowm & 255;
                const int c = nt * 256 + wnr + n * 16 + l16;
                Tt8[(((size_t)h * 16 + b) * 256 + q) * 2048 + c] = f2f8(acc[i][n][r] * 0.0078125f);
            }
}

// sim: per bh, 128x128 tiles, K=512 (bf16 2-phase core). simf f32.
__global__ __launch_bounds__(256) void k_sim(const ushort_t* __restrict__ QKbuf, float* __restrict__ simf) {
    const int wg = blockIdx.x;
    const int bh = wg >> 2, mt = (wg >> 1) & 1, ntl = wg & 1;
    const ushort_t* Qr = QKbuf;
    const ushort_t* Kr = QKbuf + (size_t)16 * 4 * 256 * 512;
    const ushort_t* A = Qr + ((size_t)bh * 256 + mt * 128) * 512;
    const ushort_t* Bm = Kr + ((size_t)bh * 256 + ntl * 128) * 512;

    fx4 acc[4][4];
#pragma unroll
    for (int i = 0; i < 4; ++i)
#pragma unroll
        for (int j = 0; j < 4; ++j) acc[i][j] = (fx4){0.f, 0.f, 0.f, 0.f};
    mfma_core(A, Bm, D_, acc);

    EPI_IDX();
    const float scale = 0.044194173824159216f;
#pragma unroll
    for (int i = 0; i < 4; ++i)
#pragma unroll
        for (int j = 0; j < 4; ++j)
#pragma unroll
            for (int r = 0; r < 4; ++r) {
                const int q = mt * 128 + wm + i * 16 + lhi * 4 + r;
                const int k = ntl * 128 + wn + j * 16 + l16;
                simf[(size_t)bh * N_ * N_ + (size_t)q * N_ + k] = acc[i][j][r] * scale;
            }
}

// softmax row -> fragment-packed P (x256). panel = bh, row-in-panel = q, K = n (nkt=4).
__global__ __launch_bounds__(64) void k_softP(const float* __restrict__ simf, u8* __restrict__ Pb8pk) {
    const int row = blockIdx.x;                 // bh*256 + q
    const int panel = row >> 8, q = row & 255;
    const float* p = simf + (size_t)row * N_;
    const int t = threadIdx.x;
    __shared__ __align__(8) u8 pl[256];
    float v0 = p[t], v1 = p[t + 64], v2 = p[t + 128], v3 = p[t + 192];
    float mx = fmaxf(fmaxf(v0, v1), fmaxf(v2, v3));
#pragma unroll
    for (int off = 32; off; off >>= 1) mx = fmaxf(mx, __shfl_xor(mx, off, 64));
    float e0 = expf(v0 - mx), e1 = expf(v1 - mx), e2 = expf(v2 - mx), e3 = expf(v3 - mx);
    float s = e0 + e1 + e2 + e3;
#pragma unroll
    for (int off = 32; off; off >>= 1) s += __shfl_xor(s, off, 64);
    const float inv = 256.0f / s;     // store P * 256 as fp8
    pl[t] = f2f8(e0 * inv); pl[t + 64] = f2f8(e1 * inv);
    pl[t + 128] = f2f8(e2 * inv); pl[t + 192] = f2f8(e3 * inv);
    __syncthreads();
    if (t < 32) {
        const int j = t >> 3, kh = (t >> 2) & 1, lhi = t & 3;
        const int half = q >> 7, mf = (q >> 4) & 7, l16 = q & 15;
        u64 v = *(const u64*)(pl + j * 64 + kh * 32 + lhi * 8);
        *(u64*)(Pb8pk + (size_t)panel * 65536 +
                (((size_t)j * 16 + half * 8 + mf) * 64 + lhi * 16 + l16) * 16 + kh * 8) = v;
    }
}

extern "C" void kernel_launch(void* const* d_in, const int* in_sizes, int n_in,
                              void* d_out, int out_size, void* d_ws, size_t ws_size,
                              hipStream_t stream)
{
    const float* x  = (const float*)d_in[0];
    const float* qw = (const float*)d_in[1];
    const float* qb = (const float*)d_in[2];
    const float* kw = (const float*)d_in[3];
    const float* kb = (const float*)d_in[4];
    const float* vw = (const float*)d_in[5];
    const float* vb = (const float*)d_in[6];

    float* out0 = (float*)d_out;
    float* out1 = out0 + (size_t)B_ * HEADS_ * N_;

    char* w = (char*)d_ws;
    u8*       vw8pk  = (u8*)w;      w += (size_t)4 * C_ * C_;              // 16.8MB packed
    u8*       qw8    = (u8*)w;      w += (size_t)4 * D_ * C_;              // 4.2MB linear
    u8*       kw8    = (u8*)w;      w += (size_t)4 * D_ * C_;              // 4.2MB linear
    ushort_t* xb     = (ushort_t*)w; w += (size_t)B_ * C_ * N_ * 2;        // 16.8MB bf16 (gating)
    u8*       xb8    = (u8*)w;      w += (size_t)B_ * C_ * N_;             // 8.4MB linear
    u8*       xbT8pk = (u8*)w;      w += (size_t)B_ * N_ * C_;             // 8.4MB packed
    ushort_t* QKbuf  = (ushort_t*)w; w += (size_t)2 * 16 * 4 * 256 * 512 * 2; // 33.6MB bf16
    u8*       Pb8pk  = (u8*)w;      w += (size_t)64 * N_ * N_;             // 4.2MB packed
    float*    simf   = (float*)w;   w += (size_t)64 * N_ * N_ * 4;         // 16.8MB
    u8*       Tt8    = (u8*)w;      w += (size_t)64 * N_ * C_;             // 33.6MB linear
    float*    xpart  = (float*)w;   w += (size_t)8 * B_ * C_ * 4;          // 1MB
    float*    xsum   = (float*)w;   w += (size_t)B_ * C_ * 4;
    float*    qsum   = (float*)w;   w += (size_t)64 * D_ * 4;
    float*    cst    = (float*)w;   w += 1024;
    float*    partv  = (float*)w;   w += (size_t)4 * 64 * C_ * 4;          // 2.1MB
    float*    part   = (float*)w;   w += (size_t)4 * 64 * N_ * 4;
    float*    score  = (float*)w;   w += (size_t)64 * N_ * 4;

    // casts / packs
    k_castw8<<<dim3(4 * D_ * C_ / 4 / 256), 256, 0, stream>>>(qw, qw8, 4 * D_ * C_, 64.0f);
    k_castw8<<<dim3(4 * D_ * C_ / 4 / 256), 256, 0, stream>>>(kw, kw8, 4 * D_ * C_, 64.0f);
    k_packvw<<<dim3(32, 32), 256, 0, stream>>>(vw, vw8pk);
    k_cast_x<<<dim3(8, 64, 16), 256, 0, stream>>>(x, xb, xb8, xbT8pk, xpart);

    // exact-f32 score path
    k_xsum2<<<dim3(8, 16), 256, 0, stream>>>(xpart, xsum);
    k_qsum <<<dim3(512), 256, 0, stream>>>(xsum, qw, qb, qsum);
    k_const<<<dim3(64), 64, 0, stream>>>(qsum, kb, cst);
    k_vecp <<<dim3(8, 4, 4), 256, 0, stream>>>(qsum, kw, partv);
    k_att  <<<dim3(64, 4), 256, 0, stream>>>(x, partv, part);
    k_score<<<dim3(16), 256, 0, stream>>>(part, cst, score, out0);

    // MFMA pipeline
    k_proj <<<dim3(256), 512, 0, stream>>>(xbT8pk, qw8, kw8, qb, kb, QKbuf);
    k_sim  <<<dim3(256), 256, 0, stream>>>(QKbuf, simf);
    k_softP<<<dim3(64 * N_), 64, 0, stream>>>(simf, Pb8pk);
    k_T8   <<<dim3(512), 512, 0, stream>>>(Pb8pk, xb8, Tt8);
    k_out  <<<dim3(512), 512, 0, stream>>>(vw8pk, vb, Tt8, score, xb, out1);
}

// Round 13
// 388.314 us; speedup vs baseline: 1.7240x; 1.0060x over previous
//
#include <hip/hip_runtime.h>
#include <hip/hip_bf16.h>
#include <hip/hip_fp8.h>

#define B_ 16
#define C_ 2048
#define N_ 256
#define HEADS_ 4
#define D_ 512

typedef unsigned int u32;
typedef unsigned char u8;
typedef unsigned short ushort_t;
typedef __attribute__((ext_vector_type(8))) short bfx8;
typedef __attribute__((ext_vector_type(4))) float fx4;

__device__ __forceinline__ unsigned short f2bs(float f) {
    __hip_bfloat16 h = __float2bfloat16(f);
    return __builtin_bit_cast(unsigned short, h);
}
__device__ __forceinline__ float bs2f(ushort_t u) {
    u32 v = ((u32)u) << 16;
    return __builtin_bit_cast(float, v);
}
__device__ __forceinline__ u8 f2f8(float f) {
    return (u8)__hip_cvt_float_to_fp8(f, __HIP_SATFINITE, __HIP_E4M3);
}
__device__ __forceinline__ void gload16(const void* g, void* l) {
    __builtin_amdgcn_global_load_lds((const __attribute__((address_space(1))) u32*)g,
                                     (__attribute__((address_space(3))) u32*)l, 16, 0, 0);
}
__device__ __forceinline__ int xcd_swz(int bid, int nwg) {
    return (bid & 7) * (nwg >> 3) + (bid >> 3);
}

#define SBAR() __builtin_amdgcn_s_barrier()
#define LGKM0() do { asm volatile("s_waitcnt lgkmcnt(0)" ::: "memory"); \
                     __builtin_amdgcn_sched_barrier(0); } while (0)
#define VMW4() asm volatile("s_waitcnt vmcnt(4)" ::: "memory")

// ======================= 256x256 merged-phase fp8 core (k_proj / k_T8) =======================
// (round-9 proven: 512 thr, 8 waves, LDS 64 KiB, 2 phases/K-tile, counted vmcnt(4))
#define STAGEF8(MAT, BUF, KH, J) do {                                         \
    const u8* s_ = (MAT) ? Bm : A;                                            \
    const int r_ = tid >> 1;                                                  \
    const int k_ = (J) * 64 + (KH) * 32 + (((tid & 1) ^ ((tid >> 3) & 1)) * 16); \
    gload16(s_ + (size_t)r_ * K + k_,                                         \
            (u8*)(&lds[MAT][BUF][KH][0][0]) + tid * 16);                      \
} while (0)

#define LDAF8(dst, BUF, KH, MH) do {                                          \
    _Pragma("unroll")                                                         \
    for (int i_ = 0; i_ < 4; ++i_)                                            \
        dst[i_] = *(const long*)(&lds[0][BUF][KH][wmr + (MH) * 64 + i_ * 16 + l16][f8off]); \
} while (0)

#define LDBF8(dst, BUF, KH) do {                                              \
    _Pragma("unroll")                                                         \
    for (int i_ = 0; i_ < 4; ++i_)                                            \
        dst[i_] = *(const long*)(&lds[1][BUF][KH][wnr + i_ * 16 + l16][f8off]); \
} while (0)

#define MMF8(aa, bb, MH) do {                                                 \
    _Pragma("unroll")                                                         \
    for (int i_ = 0; i_ < 4; ++i_) {                                          \
        _Pragma("unroll")                                                     \
        for (int n_ = 0; n_ < 4; ++n_)                                        \
            acc[(MH) * 4 + i_][n_] = __builtin_amdgcn_mfma_f32_16x16x32_fp8_fp8( \
                aa[i_], bb[n_], acc[(MH) * 4 + i_][n_], 0, 0, 0);             \
    }                                                                         \
} while (0)

#define KTILE2F8(BUF, JS1, JS2) do {                                          \
    long a0[4], a1[4], b0[4];                                                 \
    LDAF8(a0, BUF, 0, 0); LDAF8(a1, BUF, 0, 1); LDBF8(b0, BUF, 0);            \
    STAGEF8(0, BUF ^ 1, 1, JS1);                                              \
    STAGEF8(1, BUF ^ 1, 1, JS1);                                              \
    SBAR(); LGKM0();                                                          \
    __builtin_amdgcn_s_setprio(1);                                            \
    MMF8(a0, b0, 0); MMF8(a1, b0, 1);                                         \
    __builtin_amdgcn_s_setprio(0);                                            \
    VMW4();                                                                   \
    SBAR();                                                                   \
    LDAF8(a0, BUF, 1, 0); LDAF8(a1, BUF, 1, 1); LDBF8(b0, BUF, 1);            \
    STAGEF8(0, BUF, 0, JS2);                                                  \
    STAGEF8(1, BUF, 0, JS2);                                                  \
    SBAR(); LGKM0();                                                          \
    __builtin_amdgcn_s_setprio(1);                                            \
    MMF8(a0, b0, 0); MMF8(a1, b0, 1);                                         \
    __builtin_amdgcn_s_setprio(0);                                            \
    VMW4();                                                                   \
    SBAR();                                                                   \
} while (0)

typedef u8 ldsf8_t[2][2][2][256][32];   // 64 KiB

__device__ __forceinline__ void gemm256_f8(const u8* __restrict__ A,
                                           const u8* __restrict__ Bm,
                                           int K, ldsf8_t& lds, fx4 acc[8][4])
{
    const int tid = threadIdx.x;
    const int lane = tid & 63;
    const int w = tid >> 6;
    const int l16 = lane & 15, lhi = lane >> 4;
    const int f8off = (((lhi >> 1) ^ ((l16 >> 2) & 1)) * 16) + (lhi & 1) * 8;
    const int wmr = (w >> 2) * 128;
    const int wnr = (w & 3) * 64;
    const int nkt = K >> 6;                           // even, >= 4

    STAGEF8(0, 0, 0, 0); STAGEF8(1, 0, 0, 0);
    STAGEF8(0, 0, 1, 0); STAGEF8(1, 0, 1, 0);
    STAGEF8(0, 1, 0, 1); STAGEF8(1, 1, 0, 1);
    VMW4();
    SBAR();

    for (int jj = 0; jj < nkt; jj += 2) {
        const int js1a = jj + 1;
        const int js2a = (jj + 2 < nkt) ? jj + 2 : nkt - 1;
        const int js1b = js2a;
        const int js2b = (jj + 3 < nkt) ? jj + 3 : nkt - 1;
        KTILE2F8(0, js1a, js2a);
        KTILE2F8(1, js1b, js2b);
    }
    asm volatile("s_waitcnt vmcnt(0)" ::: "memory");
    SBAR();
}

#define EPI256_IDX() \
    const int lane = threadIdx.x & 63, w = threadIdx.x >> 6; \
    const int l16 = lane & 15, lhi = lane >> 4; \
    const int wmr = (w >> 2) * 128, wnr = (w & 3) * 64;

// ======================= 128x128 merged-phase fp8 core (k_out, occupancy experiment) =========
// 256 thr, 4 waves 2x2 (each 64x64, acc[4][4]=64 regs). LDS 16 KiB. Same schedule/counts as
// the 256 core (2 gloads/phase, vmcnt(4)) -> identical correctness arithmetic.
// __launch_bounds__(256,3) targets 3 waves/SIMD = 3 blocks/CU for cross-block overlap.
typedef u8 lds128_t[2][2][2][128][32];   // 16 KiB

#define STG1(MAT, BUF, KH, J) do {                                            \
    const u8* s_ = (MAT) ? Bm : A;                                            \
    const int r_ = tid >> 1;                                                  \
    const int k_ = (J) * 64 + (KH) * 32 + (((tid & 1) ^ ((tid >> 3) & 1)) * 16); \
    gload16(s_ + (size_t)r_ * K + k_,                                         \
            (u8*)(&lds[MAT][BUF][KH][0][0]) + tid * 16);                      \
} while (0)

#define LD1(dst, MAT, BUF, KH, base) do {                                     \
    _Pragma("unroll")                                                         \
    for (int i_ = 0; i_ < 4; ++i_)                                            \
        dst[i_] = *(const long*)(&lds[MAT][BUF][KH][(base) + i_ * 16 + l16][f8off]); \
} while (0)

#define MM16(aa, bb) do {                                                     \
    __builtin_amdgcn_s_setprio(1);                                            \
    _Pragma("unroll")                                                         \
    for (int i_ = 0; i_ < 4; ++i_) {                                          \
        _Pragma("unroll")                                                     \
        for (int n_ = 0; n_ < 4; ++n_)                                        \
            acc[i_][n_] = __builtin_amdgcn_mfma_f32_16x16x32_fp8_fp8(         \
                aa[i_], bb[n_], acc[i_][n_], 0, 0, 0);                        \
    }                                                                         \
    __builtin_amdgcn_s_setprio(0);                                            \
} while (0)

#define KT128(BUF, JS1, JS2) do {                                             \
    long a0[4], b0[4];                                                        \
    LD1(a0, 0, BUF, 0, wm); LD1(b0, 1, BUF, 0, wn);                           \
    STG1(0, BUF ^ 1, 1, JS1); STG1(1, BUF ^ 1, 1, JS1);                       \
    SBAR(); LGKM0();                                                          \
    MM16(a0, b0);                                                             \
    VMW4();                                                                   \
    SBAR();                                                                   \
    LD1(a0, 0, BUF, 1, wm); LD1(b0, 1, BUF, 1, wn);                           \
    STG1(0, BUF, 0, JS2); STG1(1, BUF, 0, JS2);                               \
    SBAR(); LGKM0();                                                          \
    MM16(a0, b0);                                                             \
    VMW4();                                                                   \
    SBAR();                                                                   \
} while (0)

__device__ __forceinline__ void gemm128_f8(const u8* __restrict__ A,
                                           const u8* __restrict__ Bm,
                                           int K, lds128_t& lds, fx4 acc[4][4])
{
    const int tid = threadIdx.x;       // 0..255
    const int lane = tid & 63;
    const int w = tid >> 6;            // 0..3
    const int l16 = lane & 15, lhi = lane >> 4;
    const int f8off = (((lhi >> 1) ^ ((l16 >> 2) & 1)) * 16) + (lhi & 1) * 8;
    const int wm = (w >> 1) * 64;
    const int wn = (w & 1) * 64;
    const int nkt = K >> 6;            // even, >= 4

    STG1(0, 0, 0, 0); STG1(1, 0, 0, 0);
    STG1(0, 0, 1, 0); STG1(1, 0, 1, 0);
    STG1(0, 1, 0, 1); STG1(1, 1, 0, 1);
    VMW4();
    SBAR();

    for (int jj = 0; jj < nkt; jj += 2) {
        const int js1a = jj + 1;
        const int js2a = (jj + 2 < nkt) ? jj + 2 : nkt - 1;
        const int js1b = js2a;
        const int js2b = (jj + 3 < nkt) ? jj + 3 : nkt - 1;
        KT128(0, js1a, js2a);
        KT128(1, js1b, js2b);
    }
    asm volatile("s_waitcnt vmcnt(0)" ::: "memory");
    SBAR();
}

// ---------------- 128x128 2-phase bf16 core (k_sim only), T2-swizzled ----------------
__device__ __forceinline__ void mfma_core(const ushort_t* __restrict__ A,
                                          const ushort_t* __restrict__ Bm,
                                          int K, fx4 acc[4][4])
{
    __shared__ __align__(16) ushort_t As[128 * 32];
    __shared__ __align__(16) ushort_t Bs[128 * 32];
    const int tid = threadIdx.x;
    const int lane = tid & 63, wave = tid >> 6;
    const int l16 = lane & 15, lhi = lane >> 4;
    const int swz8 = (lhi ^ ((l16 >> 1) & 3)) * 8;
    const int wm = (wave >> 1) * 64, wn = (wave & 1) * 64;

    for (int k0 = 0; k0 < K; k0 += 32) {
        const int f0 = tid, f1 = tid + 256;
        gload16(A + (size_t)(f0 >> 2) * K + k0 + (((f0 & 3) ^ ((f0 >> 3) & 3)) * 8), As + f0 * 8);
        gload16(A + (size_t)(f1 >> 2) * K + k0 + (((f1 & 3) ^ ((f1 >> 3) & 3)) * 8), As + f1 * 8);
        gload16(Bm + (size_t)(f0 >> 2) * K + k0 + (((f0 & 3) ^ ((f0 >> 3) & 3)) * 8), Bs + f0 * 8);
        gload16(Bm + (size_t)(f1 >> 2) * K + k0 + (((f1 & 3) ^ ((f1 >> 3) & 3)) * 8), Bs + f1 * 8);
        __syncthreads();
        bfx8 af[4], bfr[4];
#pragma unroll
        for (int i = 0; i < 4; ++i)
            af[i] = *(const bfx8*)(As + (wm + i * 16 + l16) * 32 + swz8);
#pragma unroll
        for (int j = 0; j < 4; ++j)
            bfr[j] = *(const bfx8*)(Bs + (wn + j * 16 + l16) * 32 + swz8);
#pragma unroll
        for (int i = 0; i < 4; ++i)
#pragma unroll
            for (int j = 0; j < 4; ++j)
                acc[i][j] = __builtin_amdgcn_mfma_f32_16x16x32_bf16(af[i], bfr[j], acc[i][j], 0, 0, 0);
        __syncthreads();
    }
}

#define EPI_IDX() \
    const int lane = threadIdx.x & 63, wave = threadIdx.x >> 6; \
    const int l16 = lane & 15, lhi = lane >> 4; \
    const int wm = (wave >> 1) * 64, wn = (wave & 1) * 64;

// ---------------- casts ----------------
__global__ __launch_bounds__(256) void k_castw8(const float* __restrict__ s, u8* __restrict__ d,
                                                int n, float scale) {
    int i = (blockIdx.x * 256 + threadIdx.x) * 4;
    if (i >= n) return;
    float4 v = *(const float4*)(s + i);
    uchar4 o = { f2f8(v.x * scale), f2f8(v.y * scale), f2f8(v.z * scale), f2f8(v.w * scale) };
    *(uchar4*)(d + i) = o;
}

__global__ __launch_bounds__(256) void k_cast_x(const float* __restrict__ x,
                                                ushort_t* __restrict__ xb, u8* __restrict__ xb8,
                                                u8* __restrict__ xbT8, float* __restrict__ xpart) {
    __shared__ float t[32][33];
    const int b = blockIdx.z, c0 = blockIdx.y * 32, n0 = blockIdx.x * 32;
    const int tn = threadIdx.x & 31, tc8 = threadIdx.x >> 5;
    const float* xp = x + ((size_t)b * C_ + c0) * N_ + n0;
#pragma unroll
    for (int p = 0; p < 4; ++p) {
        int cc = tc8 + p * 8;
        float v = xp[(size_t)cc * N_ + tn];
        t[cc][tn] = v;
        xb[((size_t)b * C_ + c0 + cc) * N_ + n0 + tn] = f2bs(v);
        xb8[((size_t)b * C_ + c0 + cc) * N_ + n0 + tn] = f2f8(v * 8.0f);
        float s = v;
#pragma unroll
        for (int o = 16; o; o >>= 1) s += __shfl_xor(s, o, 32);
        if (tn == 0) xpart[(size_t)blockIdx.x * B_ * C_ + (size_t)b * C_ + c0 + cc] = s;
    }
    __syncthreads();
#pragma unroll
    for (int p = 0; p < 4; ++p) {
        int nn = tc8 + p * 8;
        xbT8[((size_t)b * N_ + n0 + nn) * C_ + c0 + tn] = f2f8(t[tn][nn] * 8.0f);
    }
}

__global__ __launch_bounds__(256) void k_xsum2(const float* __restrict__ xpart, float* __restrict__ xsum) {
    const int c = blockIdx.x * 256 + threadIdx.x, b = blockIdx.y;
    float s = 0.f;
#pragma unroll
    for (int t = 0; t < 8; ++t) s += xpart[(size_t)t * B_ * C_ + (size_t)b * C_ + c];
    xsum[(size_t)b * C_ + c] = s;
}

// ---------------- exact-f32 score path ----------------
__global__ __launch_bounds__(256) void k_qsum(const float* __restrict__ xsum, const float* __restrict__ qw,
                                              const float* __restrict__ qb, float* __restrict__ qsum) {
    const int wave = threadIdx.x >> 6, lane = threadIdx.x & 63;
    const int row = blockIdx.x * 4 + wave;            // h*512+d, in [0, 2048)
    const int h = row >> 9, d = row & 511;
    const float* wr = qw + (size_t)row * C_;
    float acc[16];
#pragma unroll
    for (int bb = 0; bb < 16; ++bb) acc[bb] = 0.f;
    for (int it = 0; it < C_ / 64; ++it) {
        const int c = it * 64 + lane;
        const float w = wr[c];
#pragma unroll
        for (int bb = 0; bb < 16; ++bb) acc[bb] += xsum[(size_t)bb * C_ + c] * w;
    }
#pragma unroll
    for (int bb = 0; bb < 16; ++bb) {
        float s = acc[bb];
#pragma unroll
        for (int o = 32; o; o >>= 1) s += __shfl_xor(s, o, 64);
        if (lane == 0) qsum[(size_t)((bb << 2) | h) * D_ + d] = s + 256.0f * qb[row];
    }
}

__global__ __launch_bounds__(64) void k_const(const float* __restrict__ qsum, const float* __restrict__ kb,
                                              float* __restrict__ cst) {
    const int bh = blockIdx.x, h = bh & 3, lane = threadIdx.x;
    float s = 0.f;
    for (int d = lane; d < D_; d += 64) s += qsum[(size_t)bh * D_ + d] * kb[h * D_ + d];
#pragma unroll
    for (int o = 32; o; o >>= 1) s += __shfl_xor(s, o, 64);
    if (lane == 0) cst[bh] = s;
}

__global__ __launch_bounds__(256) void k_vecp(const float* __restrict__ qsum, const float* __restrict__ kw,
                                              float* __restrict__ partv) {
    const int ct = blockIdx.x, h = blockIdx.y, dsl = blockIdx.z;
    __shared__ float qs[16 * 128];
    for (int i = threadIdx.x; i < 16 * 128; i += 256) {
        int bb = i >> 7, dd = i & 127;
        qs[i] = qsum[(size_t)((bb << 2) | h) * D_ + dsl * 128 + dd];
    }
    __syncthreads();
    const int c = ct * 256 + threadIdx.x;
    const float* wp = kw + ((size_t)h * D_ + dsl * 128) * C_ + c;
    float acc[16];
#pragma unroll
    for (int bb = 0; bb < 16; ++bb) acc[bb] = 0.f;
    for (int dd = 0; dd < 128; ++dd) {
        const float w = wp[(size_t)dd * C_];
#pragma unroll
        for (int bb = 0; bb < 16; ++bb) acc[bb] += qs[bb * 128 + dd] * w;
    }
#pragma unroll
    for (int bb = 0; bb < 16; ++bb)
        partv[((size_t)dsl * 64 + ((bb << 2) | h)) * C_ + c] = acc[bb];
}

__global__ __launch_bounds__(256) void k_att(const float* __restrict__ x, const float* __restrict__ partv,
                                             float* __restrict__ part) {
    const int bh = blockIdx.x, sl = blockIdx.y, b = bh >> 2;
    __shared__ float vs[512];
    const int c0 = sl * 512;
    for (int i = threadIdx.x; i < 512; i += 256) {
        float v = 0.f;
#pragma unroll
        for (int dsl = 0; dsl < 4; ++dsl) v += partv[((size_t)dsl * 64 + bh) * C_ + c0 + i];
        vs[i] = v;
    }
    __syncthreads();
    float a = 0.f;
    const float* xp = x + ((size_t)b * C_ + c0) * N_ + threadIdx.x;
#pragma unroll 8
    for (int c = 0; c < 512; ++c) a += vs[c] * xp[(size_t)c * N_];
    part[((size_t)sl * 64 + bh) * N_ + threadIdx.x] = a;
}

__global__ __launch_bounds__(256) void k_score(const float* __restrict__ part, const float* __restrict__ cst,
                                               float* __restrict__ score, float* __restrict__ out0) {
    const int b = blockIdx.x, k = threadIdx.x;
    const float scale = 0.044194173824159216f;
    float a[4];
#pragma unroll
    for (int h = 0; h < 4; ++h) {
        const int bh = b * 4 + h;
        float s = cst[bh];
#pragma unroll
        for (int sl = 0; sl < 4; ++sl) s += part[((size_t)sl * 64 + bh) * N_ + k];
        a[h] = s * scale;
    }
    float mx = fmaxf(fmaxf(a[0], a[1]), fmaxf(a[2], a[3]));
    float e0 = expf(a[0] - mx), e1 = expf(a[1] - mx), e2 = expf(a[2] - mx), e3 = expf(a[3] - mx);
    float inv = 1.0f / (e0 + e1 + e2 + e3);
    float r[4] = { e0 * inv, e1 * inv, e2 * inv, e3 * inv };
#pragma unroll
    for (int h = 0; h < 4; ++h) {
        score[(size_t)(b * 4 + h) * N_ + k] = r[h];
        out0[(size_t)(b * 4 + h) * N_ + k] = r[h];
    }
}

// ---------------- fp8 MFMA GEMMs ----------------
// proj: M=(b,n)=4096, N=(qk,h,d)=4096, K=2048 (256-core).
__global__ __launch_bounds__(512, 2) void k_proj(const u8* __restrict__ xbT8,
                                                 const u8* __restrict__ qw8, const u8* __restrict__ kw8,
                                                 const float* __restrict__ qb, const float* __restrict__ kb,
                                                 ushort_t* __restrict__ QKbuf) {
    __shared__ __align__(16) ldsf8_t lds;
    const int wg = xcd_swz(blockIdx.x, 256);
    const int quad = wg >> 2;
    const int mt = quad >> 2;                 // 0..15
    const int nt = (quad & 3) * 4 + (wg & 3); // 0..15
    const int c0 = nt * 256;
    const int qk = c0 >> 11;
    const int rem = c0 & 2047;                // h*512 + d0
    const u8* A  = xbT8 + (size_t)mt * 256 * C_;
    const u8* Bm = (qk ? kw8 : qw8) + (size_t)rem * C_;
    const float* bias  = (qk ? kb : qb) + rem;
    const int K = C_;

    fx4 acc[8][4];
#pragma unroll
    for (int i = 0; i < 8; ++i)
#pragma unroll
        for (int j = 0; j < 4; ++j) acc[i][j] = (fx4){0.f, 0.f, 0.f, 0.f};
    gemm256_f8(A, Bm, K, lds, acc);

    EPI256_IDX();
#pragma unroll
    for (int i = 0; i < 8; ++i)
#pragma unroll
        for (int n = 0; n < 4; ++n)
#pragma unroll
            for (int r = 0; r < 4; ++r) {
                const int gr = mt * 256 + wmr + i * 16 + lhi * 4 + r;
                const int bq = gr >> 8, nn = gr & 255;
                const int lc = wnr + n * 16 + l16;
                const int hh = (rem + lc) >> 9, dl = (rem + lc) & 511;
                const float v = acc[i][n][r] * (1.0f / 512.0f) + bias[lc];
                QKbuf[((((size_t)(qk * 16 + bq) * 4 + hh) * 256) + nn) * 512 + dl] = f2bs(v);
            }
}

// out: per h, M=e=2048, N=(b,n)=4096, K=2048. 128-core, 2048 wg x 256 thr, 3 blocks/CU target.
__global__ __launch_bounds__(256, 3) void k_out(const u8* __restrict__ vw8, const float* __restrict__ vb,
                                                const u8* __restrict__ Tt8, const float* __restrict__ score,
                                                const ushort_t* __restrict__ xb, float* __restrict__ out1) {
    __shared__ __align__(16) lds128_t lds;
    const int wg = xcd_swz(blockIdx.x, 2048);
    const int h = wg >> 9, l = wg & 511;
    const int mt = l >> 5, nt = l & 31;       // mt 0..15, nt 0..31
    const u8* A  = vw8 + (size_t)h * C_ * C_ + (size_t)mt * 128 * C_;
    const u8* Bm = Tt8 + (size_t)h * 16 * N_ * C_ + (size_t)nt * 128 * C_;
    const int K = C_;

    fx4 acc[4][4];
#pragma unroll
    for (int i = 0; i < 4; ++i)
#pragma unroll
        for (int j = 0; j < 4; ++j) acc[i][j] = (fx4){0.f, 0.f, 0.f, 0.f};
    gemm128_f8(A, Bm, K, lds, acc);

    const int lane = threadIdx.x & 63, w = threadIdx.x >> 6;
    const int l16 = lane & 15, lhi = lane >> 4;
    const int wm = (w >> 1) * 64, wn = (w & 1) * 64;
#pragma unroll
    for (int i = 0; i < 4; ++i)
#pragma unroll
        for (int n = 0; n < 4; ++n)
#pragma unroll
            for (int r = 0; r < 4; ++r) {
                const int e = mt * 128 + wm + i * 16 + lhi * 4 + r;
                const int col = nt * 128 + wn + n * 16 + l16;
                const int b = col >> 8, nn = col & 255;
                float v = acc[i][n][r] * (1.0f / 1024.0f) + vb[h * C_ + e]
                        + score[(size_t)(b * 4 + h) * N_ + nn] * bs2f(xb[((size_t)b * C_ + e) * N_ + nn]);
                out1[((size_t)(b * 4 + h) * C_ + e) * N_ + nn] = v;
            }
}

// T: per b, M=(h,q)=1024, N=c=2048, K=256 (256-core).
__global__ __launch_bounds__(512, 2) void k_T8(const u8* __restrict__ Pb8, const u8* __restrict__ xb8,
                                               u8* __restrict__ Tt8) {
    __shared__ __align__(16) ldsf8_t lds;
    const int wg = xcd_swz(blockIdx.x, 512);
    const int b = wg >> 5, l = wg & 31;       // 16 b x (4 mt x 8 nt)
    const int mt = l >> 3, nt = l & 7;
    const u8* A  = Pb8 + ((size_t)b * 1024 + mt * 256) * 256;
    const u8* Bm = xb8 + ((size_t)b * 2048 + nt * 256) * 256;
    const int K = N_;

    fx4 acc[8][4];
#pragma unroll
    for (int i = 0; i < 8; ++i)
#pragma unroll
        for (int j = 0; j < 4; ++j) acc[i][j] = (fx4){0.f, 0.f, 0.f, 0.f};
    gemm256_f8(A, Bm, K, lds, acc);

    EPI256_IDX();
#pragma unroll
    for (int i = 0; i < 8; ++i)
#pragma unroll
        for (int n = 0; n < 4; ++n)
#pragma unroll
            for (int r = 0; r < 4; ++r) {
                const int rowm = mt * 256 + wmr + i * 16 + lhi * 4 + r;
                const int h = rowm >> 8, q = rowm & 255;
                const int c = nt * 256 + wnr + n * 16 + l16;
                Tt8[(((size_t)h * 16 + b) * 256 + q) * 2048 + c] = f2f8(acc[i][n][r] * 0.0078125f);
            }
}

// sim: per bh, 128x128 tiles, K=512 (bf16 2-phase core). simf f32.
__global__ __launch_bounds__(256) void k_sim(const ushort_t* __restrict__ QKbuf, float* __restrict__ simf) {
    const int wg = blockIdx.x;
    const int bh = wg >> 2, mt = (wg >> 1) & 1, ntl = wg & 1;
    const ushort_t* Qr = QKbuf;
    const ushort_t* Kr = QKbuf + (size_t)16 * 4 * 256 * 512;
    const ushort_t* A = Qr + ((size_t)bh * 256 + mt * 128) * 512;
    const ushort_t* Bm = Kr + ((size_t)bh * 256 + ntl * 128) * 512;

    fx4 acc[4][4];
#pragma unroll
    for (int i = 0; i < 4; ++i)
#pragma unroll
        for (int j = 0; j < 4; ++j) acc[i][j] = (fx4){0.f, 0.f, 0.f, 0.f};
    mfma_core(A, Bm, D_, acc);

    EPI_IDX();
    const float scale = 0.044194173824159216f;
#pragma unroll
    for (int i = 0; i < 4; ++i)
#pragma unroll
        for (int j = 0; j < 4; ++j)
#pragma unroll
            for (int r = 0; r < 4; ++r) {
                const int q = mt * 128 + wm + i * 16 + lhi * 4 + r;
                const int k = ntl * 128 + wn + j * 16 + l16;
                simf[(size_t)bh * N_ * N_ + (size_t)q * N_ + k] = acc[i][j][r] * scale;
            }
}

__global__ __launch_bounds__(64) void k_softP(const float* __restrict__ simf, u8* __restrict__ Pb8) {
    const size_t row = blockIdx.x;
    const float* p = simf + row * N_;
    u8* o = Pb8 + row * N_;
    const int t = threadIdx.x;
    float v0 = p[t], v1 = p[t + 64], v2 = p[t + 128], v3 = p[t + 192];
    float mx = fmaxf(fmaxf(v0, v1), fmaxf(v2, v3));
#pragma unroll
    for (int off = 32; off; off >>= 1) mx = fmaxf(mx, __shfl_xor(mx, off, 64));
    float e0 = expf(v0 - mx), e1 = expf(v1 - mx), e2 = expf(v2 - mx), e3 = expf(v3 - mx);
    float s = e0 + e1 + e2 + e3;
#pragma unroll
    for (int off = 32; off; off >>= 1) s += __shfl_xor(s, off, 64);
    const float inv = 256.0f / s;     // store P * 256 as fp8
    o[t] = f2f8(e0 * inv); o[t + 64] = f2f8(e1 * inv);
    o[t + 128] = f2f8(e2 * inv); o[t + 192] = f2f8(e3 * inv);
}

extern "C" void kernel_launch(void* const* d_in, const int* in_sizes, int n_in,
                              void* d_out, int out_size, void* d_ws, size_t ws_size,
                              hipStream_t stream)
{
    const float* x  = (const float*)d_in[0];
    const float* qw = (const float*)d_in[1];
    const float* qb = (const float*)d_in[2];
    const float* kw = (const float*)d_in[3];
    const float* kb = (const float*)d_in[4];
    const float* vw = (const float*)d_in[5];
    const float* vb = (const float*)d_in[6];

    float* out0 = (float*)d_out;
    float* out1 = out0 + (size_t)B_ * HEADS_ * N_;

    char* w = (char*)d_ws;
    u8*       vw8  = (u8*)w;        w += (size_t)4 * C_ * C_;              // 16.8MB
    u8*       qw8  = (u8*)w;        w += (size_t)4 * D_ * C_;              // 4.2MB
    u8*       kw8  = (u8*)w;        w += (size_t)4 * D_ * C_;              // 4.2MB
    ushort_t* xb   = (ushort_t*)w;  w += (size_t)B_ * C_ * N_ * 2;         // 16.8MB (bf16, gating)
    u8*       xb8  = (u8*)w;        w += (size_t)B_ * C_ * N_;             // 8.4MB
    u8*       xbT8 = (u8*)w;        w += (size_t)B_ * N_ * C_;             // 8.4MB
    ushort_t* QKbuf= (ushort_t*)w;  w += (size_t)2 * 16 * 4 * 256 * 512 * 2; // 33.6MB bf16
    u8*       Pb8  = (u8*)w;        w += (size_t)64 * N_ * N_;             // 4.2MB
    float*    simf = (float*)w;     w += (size_t)64 * N_ * N_ * 4;         // 16.8MB
    u8*       Tt8  = (u8*)w;        w += (size_t)64 * N_ * C_;             // 33.6MB
    float*    xpart= (float*)w;     w += (size_t)8 * B_ * C_ * 4;          // 1MB
    float*    xsum = (float*)w;     w += (size_t)B_ * C_ * 4;
    float*    qsum = (float*)w;     w += (size_t)64 * D_ * 4;
    float*    cst  = (float*)w;     w += 1024;
    float*    partv= (float*)w;     w += (size_t)4 * 64 * C_ * 4;          // 2.1MB
    float*    part = (float*)w;     w += (size_t)4 * 64 * N_ * 4;
    float*    score= (float*)w;     w += (size_t)64 * N_ * 4;

    // casts (weights x64 -> fp8; x -> bf16 + fp8 x8 + transposed fp8 x8)
    k_castw8<<<dim3(4 * D_ * C_ / 4 / 256), 256, 0, stream>>>(qw, qw8, 4 * D_ * C_, 64.0f);
    k_castw8<<<dim3(4 * D_ * C_ / 4 / 256), 256, 0, stream>>>(kw, kw8, 4 * D_ * C_, 64.0f);
    k_castw8<<<dim3(4 * C_ * C_ / 4 / 256), 256, 0, stream>>>(vw, vw8, 4 * C_ * C_, 64.0f);
    k_cast_x<<<dim3(8, 64, 16), 256, 0, stream>>>(x, xb, xb8, xbT8, xpart);

    // exact-f32 score path
    k_xsum2<<<dim3(8, 16), 256, 0, stream>>>(xpart, xsum);
    k_qsum <<<dim3(512), 256, 0, stream>>>(xsum, qw, qb, qsum);
    k_const<<<dim3(64), 64, 0, stream>>>(qsum, kb, cst);
    k_vecp <<<dim3(8, 4, 4), 256, 0, stream>>>(qsum, kw, partv);
    k_att  <<<dim3(64, 4), 256, 0, stream>>>(x, partv, part);
    k_score<<<dim3(16), 256, 0, stream>>>(part, cst, score, out0);

    // MFMA pipeline
    k_proj <<<dim3(256), 512, 0, stream>>>(xbT8, qw8, kw8, qb, kb, QKbuf);
    k_sim  <<<dim3(256), 256, 0, stream>>>(QKbuf, simf);
    k_softP<<<dim3(64 * N_), 64, 0, stream>>>(simf, Pb8);
    k_T8   <<<dim3(512), 512, 0, stream>>>(Pb8, xb8, Tt8);
    k_out  <<<dim3(2048), 256, 0, stream>>>(vw8, vb, Tt8, score, xb, out1);
}

// Round 14
// 360.339 us; speedup vs baseline: 1.8579x; 1.0776x over previous
//
#include <hip/hip_runtime.h>
#include <hip/hip_bf16.h>
#include <hip/hip_fp8.h>

#define B_ 16
#define C_ 2048
#define N_ 256
#define HEADS_ 4
#define D_ 512

typedef unsigned int u32;
typedef unsigned char u8;
typedef unsigned short ushort_t;
typedef __attribute__((ext_vector_type(8))) short bfx8;
typedef __attribute__((ext_vector_type(4))) float fx4;

__device__ __forceinline__ unsigned short f2bs(float f) {
    __hip_bfloat16 h = __float2bfloat16(f);
    return __builtin_bit_cast(unsigned short, h);
}
__device__ __forceinline__ float bs2f(ushort_t u) {
    u32 v = ((u32)u) << 16;
    return __builtin_bit_cast(float, v);
}
__device__ __forceinline__ u8 f2f8(float f) {
    return (u8)__hip_cvt_float_to_fp8(f, __HIP_SATFINITE, __HIP_E4M3);
}
__device__ __forceinline__ void gload16(const void* g, void* l) {
    __builtin_amdgcn_global_load_lds((const __attribute__((address_space(1))) u32*)g,
                                     (__attribute__((address_space(3))) u32*)l, 16, 0, 0);
}
__device__ __forceinline__ int xcd_swz(int bid, int nwg) {
    return (bid & 7) * (nwg >> 3) + (bid >> 3);
}

#define SBAR() __builtin_amdgcn_s_barrier()
#define LGKM0() do { asm volatile("s_waitcnt lgkmcnt(0)" ::: "memory"); \
                     __builtin_amdgcn_sched_barrier(0); } while (0)
#define VMW4() asm volatile("s_waitcnt vmcnt(4)" ::: "memory")
#define VMW3() asm volatile("s_waitcnt vmcnt(3)" ::: "memory")
#define VMW2() asm volatile("s_waitcnt vmcnt(2)" ::: "memory")
#define VMW1() asm volatile("s_waitcnt vmcnt(1)" ::: "memory")

// ======================= 256x256 merged-phase fp8 core (k_proj / k_T8) =======================
// (round-9 proven: 512 thr, 8 waves, LDS 64 KiB, 2 phases/K-tile, counted vmcnt(4))
#define STAGEF8(MAT, BUF, KH, J) do {                                         \
    const u8* s_ = (MAT) ? Bm : A;                                            \
    const int r_ = tid >> 1;                                                  \
    const int k_ = (J) * 64 + (KH) * 32 + (((tid & 1) ^ ((tid >> 3) & 1)) * 16); \
    gload16(s_ + (size_t)r_ * K + k_,                                         \
            (u8*)(&lds[MAT][BUF][KH][0][0]) + tid * 16);                      \
} while (0)

#define LDAF8(dst, BUF, KH, MH) do {                                          \
    _Pragma("unroll")                                                         \
    for (int i_ = 0; i_ < 4; ++i_)                                            \
        dst[i_] = *(const long*)(&lds[0][BUF][KH][wmr + (MH) * 64 + i_ * 16 + l16][f8off]); \
} while (0)

#define LDBF8(dst, BUF, KH) do {                                              \
    _Pragma("unroll")                                                         \
    for (int i_ = 0; i_ < 4; ++i_)                                            \
        dst[i_] = *(const long*)(&lds[1][BUF][KH][wnr + i_ * 16 + l16][f8off]); \
} while (0)

#define MMF8(aa, bb, MH) do {                                                 \
    _Pragma("unroll")                                                         \
    for (int i_ = 0; i_ < 4; ++i_) {                                          \
        _Pragma("unroll")                                                     \
        for (int n_ = 0; n_ < 4; ++n_)                                        \
            acc[(MH) * 4 + i_][n_] = __builtin_amdgcn_mfma_f32_16x16x32_fp8_fp8( \
                aa[i_], bb[n_], acc[(MH) * 4 + i_][n_], 0, 0, 0);             \
    }                                                                         \
} while (0)

#define KTILE2F8(BUF, JS1, JS2) do {                                          \
    long a0[4], a1[4], b0[4];                                                 \
    LDAF8(a0, BUF, 0, 0); LDAF8(a1, BUF, 0, 1); LDBF8(b0, BUF, 0);            \
    STAGEF8(0, BUF ^ 1, 1, JS1);                                              \
    STAGEF8(1, BUF ^ 1, 1, JS1);                                              \
    SBAR(); LGKM0();                                                          \
    __builtin_amdgcn_s_setprio(1);                                            \
    MMF8(a0, b0, 0); MMF8(a1, b0, 1);                                         \
    __builtin_amdgcn_s_setprio(0);                                            \
    VMW4();                                                                   \
    SBAR();                                                                   \
    LDAF8(a0, BUF, 1, 0); LDAF8(a1, BUF, 1, 1); LDBF8(b0, BUF, 1);            \
    STAGEF8(0, BUF, 0, JS2);                                                  \
    STAGEF8(1, BUF, 0, JS2);                                                  \
    SBAR(); LGKM0();                                                          \
    __builtin_amdgcn_s_setprio(1);                                            \
    MMF8(a0, b0, 0); MMF8(a1, b0, 1);                                         \
    __builtin_amdgcn_s_setprio(0);                                            \
    VMW4();                                                                   \
    SBAR();                                                                   \
} while (0)

typedef u8 ldsf8_t[2][2][2][256][32];   // 64 KiB

__device__ __forceinline__ void gemm256_f8(const u8* __restrict__ A,
                                           const u8* __restrict__ Bm,
                                           int K, ldsf8_t& lds, fx4 acc[8][4])
{
    const int tid = threadIdx.x;
    const int lane = tid & 63;
    const int w = tid >> 6;
    const int l16 = lane & 15, lhi = lane >> 4;
    const int f8off = (((lhi >> 1) ^ ((l16 >> 2) & 1)) * 16) + (lhi & 1) * 8;
    const int wmr = (w >> 2) * 128;
    const int wnr = (w & 3) * 64;
    const int nkt = K >> 6;                           // even, >= 4

    STAGEF8(0, 0, 0, 0); STAGEF8(1, 0, 0, 0);
    STAGEF8(0, 0, 1, 0); STAGEF8(1, 0, 1, 0);
    STAGEF8(0, 1, 0, 1); STAGEF8(1, 1, 0, 1);
    VMW4();
    SBAR();

    for (int jj = 0; jj < nkt; jj += 2) {
        const int js1a = jj + 1;
        const int js2a = (jj + 2 < nkt) ? jj + 2 : nkt - 1;
        const int js1b = js2a;
        const int js2b = (jj + 3 < nkt) ? jj + 3 : nkt - 1;
        KTILE2F8(0, js1a, js2a);
        KTILE2F8(1, js1b, js2b);
    }
    asm volatile("s_waitcnt vmcnt(0)" ::: "memory");
    SBAR();
}

#define EPI256_IDX() \
    const int lane = threadIdx.x & 63, w = threadIdx.x >> 6; \
    const int l16 = lane & 15, lhi = lane >> 4; \
    const int wmr = (w >> 2) * 128, wnr = (w & 3) * 64;

// ============ 128x256 merged-phase fp8 core (k_out): 2 blocks/CU for overlap ============
// 512 thr = 8 waves (2Mw x 4Nw), wave tile 64x64, acc[4][4]=64 AGPR. LDS 48 KiB
// (A 16KB + B 32KB) -> 2 blocks/CU at <=128 unified regs (__launch_bounds__(512,4)).
// Regions/K-tile(64): RA = A both kh (waves 0-3 kh0, 4-7 kh1, 1 gload/thr),
// RB0/RB1 = B per kh (1 gload/thr). 2 phases/tile:
//   ph0: read kh0 frags; stage RA(j+1), RB1(j+1); bar; lgkm0; 16 MFMA; vmcnt(3); bar
//   ph1: read kh1 frags; stage RB0(j+2);          bar; lgkm0; 16 MFMA; vmcnt(2); bar
// FIFO audit: ph0-end needs RA(j)/RB1(j) [staged j-1 ph0] -> 3 younger outstanding;
// ph1-end needs RA(j+1) [j ph0] -> 2 younger (RB1(j+1), RB0(j+2)). Prologue: RA(0),
// RB0(0), RB1(0), RB0(1) then vmcnt(1). Tail clamps are dead re-stages (counts exact).
#define STGA2(BUF, J) do {                                                    \
    const int t_ = tid & 255;                                                 \
    const int kh_ = tid >> 8;                                                 \
    const int r_ = t_ >> 1;                                                   \
    const int k_ = (J) * 64 + kh_ * 32 + (((tid & 1) ^ ((tid >> 3) & 1)) * 16); \
    gload16(A + (size_t)r_ * K + k_,                                          \
            (u8*)(&ldsA[BUF][kh_][0][0]) + t_ * 16);                          \
} while (0)

#define STGB2(BUF, KH, J) do {                                                \
    const int r_ = tid >> 1;                                                  \
    const int k_ = (J) * 64 + (KH) * 32 + (((tid & 1) ^ ((tid >> 3) & 1)) * 16); \
    gload16(Bm + (size_t)r_ * K + k_,                                         \
            (u8*)(&ldsB[BUF][KH][0][0]) + tid * 16);                          \
} while (0)

#define LDA2(dst, BUF, KH) do {                                               \
    _Pragma("unroll")                                                         \
    for (int i_ = 0; i_ < 4; ++i_)                                            \
        dst[i_] = *(const long*)(&ldsA[BUF][KH][wma + i_ * 16 + l16][f8off]); \
} while (0)

#define LDB2(dst, BUF, KH) do {                                               \
    _Pragma("unroll")                                                         \
    for (int i_ = 0; i_ < 4; ++i_)                                            \
        dst[i_] = *(const long*)(&ldsB[BUF][KH][wnb + i_ * 16 + l16][f8off]); \
} while (0)

#define MM16W(aa, bb) do {                                                    \
    __builtin_amdgcn_s_setprio(1);                                            \
    _Pragma("unroll")                                                         \
    for (int i_ = 0; i_ < 4; ++i_) {                                          \
        _Pragma("unroll")                                                     \
        for (int n_ = 0; n_ < 4; ++n_)                                        \
            acc[i_][n_] = __builtin_amdgcn_mfma_f32_16x16x32_fp8_fp8(         \
                aa[i_], bb[n_], acc[i_][n_], 0, 0, 0);                        \
    }                                                                         \
    __builtin_amdgcn_s_setprio(0);                                            \
} while (0)

#define KTW(BUF, JS1, JS2) do {                                               \
    long a0[4], b0[4];                                                        \
    /* ph0 (kh0) */                                                           \
    LDA2(a0, BUF, 0); LDB2(b0, BUF, 0);                                       \
    STGA2(BUF ^ 1, JS1);                                                      \
    STGB2(BUF ^ 1, 1, JS1);                                                   \
    SBAR(); LGKM0();                                                          \
    MM16W(a0, b0);                                                            \
    VMW3();                                                                   \
    SBAR();                                                                   \
    /* ph1 (kh1) */                                                           \
    LDA2(a0, BUF, 1); LDB2(b0, BUF, 1);                                       \
    STGB2(BUF, 0, JS2);                                                       \
    SBAR(); LGKM0();                                                          \
    MM16W(a0, b0);                                                            \
    VMW2();                                                                   \
    SBAR();                                                                   \
} while (0)

typedef u8 ldsA_t[2][2][128][32];   // 16 KiB
typedef u8 ldsB_t2[2][2][256][32];  // 32 KiB

__device__ __forceinline__ void gemm128x256_f8(const u8* __restrict__ A,
                                               const u8* __restrict__ Bm,
                                               int K, ldsA_t& ldsA, ldsB_t2& ldsB,
                                               fx4 acc[4][4])
{
    const int tid = threadIdx.x;       // 0..511
    const int lane = tid & 63;
    const int w = tid >> 6;            // 0..7
    const int l16 = lane & 15, lhi = lane >> 4;
    const int f8off = (((lhi >> 1) ^ ((l16 >> 2) & 1)) * 16) + (lhi & 1) * 8;
    const int wma = (w >> 2) * 64;     // A rows (128 total, 2 M-waves)
    const int wnb = (w & 3) * 64;      // B rows (256 total, 4 N-waves)
    const int nkt = K >> 6;            // even, >= 4

    // prologue: RA(0), RB0(0), RB1(0), RB0(1); tile0 ready when 1 outstanding.
    STGA2(0, 0);
    STGB2(0, 0, 0);
    STGB2(0, 1, 0);
    STGB2(1, 0, 1);
    VMW1();
    SBAR();

    for (int jj = 0; jj < nkt; jj += 2) {
        const int js1a = jj + 1;                              // < nkt always
        const int js2a = (jj + 2 < nkt) ? jj + 2 : nkt - 1;
        const int js1b = js2a;
        const int js2b = (jj + 3 < nkt) ? jj + 3 : nkt - 1;
        KTW(0, js1a, js2a);
        KTW(1, js1b, js2b);
    }
    asm volatile("s_waitcnt vmcnt(0)" ::: "memory");
    SBAR();
}

// ---------------- 128x128 2-phase bf16 core (k_sim only), T2-swizzled ----------------
__device__ __forceinline__ void mfma_core(const ushort_t* __restrict__ A,
                                          const ushort_t* __restrict__ Bm,
                                          int K, fx4 acc[4][4])
{
    __shared__ __align__(16) ushort_t As[128 * 32];
    __shared__ __align__(16) ushort_t Bs[128 * 32];
    const int tid = threadIdx.x;
    const int lane = tid & 63, wave = tid >> 6;
    const int l16 = lane & 15, lhi = lane >> 4;
    const int swz8 = (lhi ^ ((l16 >> 1) & 3)) * 8;
    const int wm = (wave >> 1) * 64, wn = (wave & 1) * 64;

    for (int k0 = 0; k0 < K; k0 += 32) {
        const int f0 = tid, f1 = tid + 256;
        gload16(A + (size_t)(f0 >> 2) * K + k0 + (((f0 & 3) ^ ((f0 >> 3) & 3)) * 8), As + f0 * 8);
        gload16(A + (size_t)(f1 >> 2) * K + k0 + (((f1 & 3) ^ ((f1 >> 3) & 3)) * 8), As + f1 * 8);
        gload16(Bm + (size_t)(f0 >> 2) * K + k0 + (((f0 & 3) ^ ((f0 >> 3) & 3)) * 8), Bs + f0 * 8);
        gload16(Bm + (size_t)(f1 >> 2) * K + k0 + (((f1 & 3) ^ ((f1 >> 3) & 3)) * 8), Bs + f1 * 8);
        __syncthreads();
        bfx8 af[4], bfr[4];
#pragma unroll
        for (int i = 0; i < 4; ++i)
            af[i] = *(const bfx8*)(As + (wm + i * 16 + l16) * 32 + swz8);
#pragma unroll
        for (int j = 0; j < 4; ++j)
            bfr[j] = *(const bfx8*)(Bs + (wn + j * 16 + l16) * 32 + swz8);
#pragma unroll
        for (int i = 0; i < 4; ++i)
#pragma unroll
            for (int j = 0; j < 4; ++j)
                acc[i][j] = __builtin_amdgcn_mfma_f32_16x16x32_bf16(af[i], bfr[j], acc[i][j], 0, 0, 0);
        __syncthreads();
    }
}

#define EPI_IDX() \
    const int lane = threadIdx.x & 63, wave = threadIdx.x >> 6; \
    const int l16 = lane & 15, lhi = lane >> 4; \
    const int wm = (wave >> 1) * 64, wn = (wave & 1) * 64;

// ---------------- casts ----------------
__global__ __launch_bounds__(256) void k_castw8(const float* __restrict__ s, u8* __restrict__ d,
                                                int n, float scale) {
    int i = (blockIdx.x * 256 + threadIdx.x) * 4;
    if (i >= n) return;
    float4 v = *(const float4*)(s + i);
    uchar4 o = { f2f8(v.x * scale), f2f8(v.y * scale), f2f8(v.z * scale), f2f8(v.w * scale) };
    *(uchar4*)(d + i) = o;
}

__global__ __launch_bounds__(256) void k_cast_x(const float* __restrict__ x,
                                                ushort_t* __restrict__ xb, u8* __restrict__ xb8,
                                                u8* __restrict__ xbT8, float* __restrict__ xpart) {
    __shared__ float t[32][33];
    const int b = blockIdx.z, c0 = blockIdx.y * 32, n0 = blockIdx.x * 32;
    const int tn = threadIdx.x & 31, tc8 = threadIdx.x >> 5;
    const float* xp = x + ((size_t)b * C_ + c0) * N_ + n0;
#pragma unroll
    for (int p = 0; p < 4; ++p) {
        int cc = tc8 + p * 8;
        float v = xp[(size_t)cc * N_ + tn];
        t[cc][tn] = v;
        xb[((size_t)b * C_ + c0 + cc) * N_ + n0 + tn] = f2bs(v);
        xb8[((size_t)b * C_ + c0 + cc) * N_ + n0 + tn] = f2f8(v * 8.0f);
        float s = v;
#pragma unroll
        for (int o = 16; o; o >>= 1) s += __shfl_xor(s, o, 32);
        if (tn == 0) xpart[(size_t)blockIdx.x * B_ * C_ + (size_t)b * C_ + c0 + cc] = s;
    }
    __syncthreads();
#pragma unroll
    for (int p = 0; p < 4; ++p) {
        int nn = tc8 + p * 8;
        xbT8[((size_t)b * N_ + n0 + nn) * C_ + c0 + tn] = f2f8(t[tn][nn] * 8.0f);
    }
}

__global__ __launch_bounds__(256) void k_xsum2(const float* __restrict__ xpart, float* __restrict__ xsum) {
    const int c = blockIdx.x * 256 + threadIdx.x, b = blockIdx.y;
    float s = 0.f;
#pragma unroll
    for (int t = 0; t < 8; ++t) s += xpart[(size_t)t * B_ * C_ + (size_t)b * C_ + c];
    xsum[(size_t)b * C_ + c] = s;
}

// ---------------- exact-f32 score path ----------------
__global__ __launch_bounds__(256) void k_qsum(const float* __restrict__ xsum, const float* __restrict__ qw,
                                              const float* __restrict__ qb, float* __restrict__ qsum) {
    const int wave = threadIdx.x >> 6, lane = threadIdx.x & 63;
    const int row = blockIdx.x * 4 + wave;            // h*512+d, in [0, 2048)
    const int h = row >> 9, d = row & 511;
    const float* wr = qw + (size_t)row * C_;
    float acc[16];
#pragma unroll
    for (int bb = 0; bb < 16; ++bb) acc[bb] = 0.f;
    for (int it = 0; it < C_ / 64; ++it) {
        const int c = it * 64 + lane;
        const float w = wr[c];
#pragma unroll
        for (int bb = 0; bb < 16; ++bb) acc[bb] += xsum[(size_t)bb * C_ + c] * w;
    }
#pragma unroll
    for (int bb = 0; bb < 16; ++bb) {
        float s = acc[bb];
#pragma unroll
        for (int o = 32; o; o >>= 1) s += __shfl_xor(s, o, 64);
        if (lane == 0) qsum[(size_t)((bb << 2) | h) * D_ + d] = s + 256.0f * qb[row];
    }
}

__global__ __launch_bounds__(64) void k_const(const float* __restrict__ qsum, const float* __restrict__ kb,
                                              float* __restrict__ cst) {
    const int bh = blockIdx.x, h = bh & 3, lane = threadIdx.x;
    float s = 0.f;
    for (int d = lane; d < D_; d += 64) s += qsum[(size_t)bh * D_ + d] * kb[h * D_ + d];
#pragma unroll
    for (int o = 32; o; o >>= 1) s += __shfl_xor(s, o, 64);
    if (lane == 0) cst[bh] = s;
}

__global__ __launch_bounds__(256) void k_vecp(const float* __restrict__ qsum, const float* __restrict__ kw,
                                              float* __restrict__ partv) {
    const int ct = blockIdx.x, h = blockIdx.y, dsl = blockIdx.z;
    __shared__ float qs[16 * 128];
    for (int i = threadIdx.x; i < 16 * 128; i += 256) {
        int bb = i >> 7, dd = i & 127;
        qs[i] = qsum[(size_t)((bb << 2) | h) * D_ + dsl * 128 + dd];
    }
    __syncthreads();
    const int c = ct * 256 + threadIdx.x;
    const float* wp = kw + ((size_t)h * D_ + dsl * 128) * C_ + c;
    float acc[16];
#pragma unroll
    for (int bb = 0; bb < 16; ++bb) acc[bb] = 0.f;
    for (int dd = 0; dd < 128; ++dd) {
        const float w = wp[(size_t)dd * C_];
#pragma unroll
        for (int bb = 0; bb < 16; ++bb) acc[bb] += qs[bb * 128 + dd] * w;
    }
#pragma unroll
    for (int bb = 0; bb < 16; ++bb)
        partv[((size_t)dsl * 64 + ((bb << 2) | h)) * C_ + c] = acc[bb];
}

__global__ __launch_bounds__(256) void k_att(const float* __restrict__ x, const float* __restrict__ partv,
                                             float* __restrict__ part) {
    const int bh = blockIdx.x, sl = blockIdx.y, b = bh >> 2;
    __shared__ float vs[512];
    const int c0 = sl * 512;
    for (int i = threadIdx.x; i < 512; i += 256) {
        float v = 0.f;
#pragma unroll
        for (int dsl = 0; dsl < 4; ++dsl) v += partv[((size_t)dsl * 64 + bh) * C_ + c0 + i];
        vs[i] = v;
    }
    __syncthreads();
    float a = 0.f;
    const float* xp = x + ((size_t)b * C_ + c0) * N_ + threadIdx.x;
#pragma unroll 8
    for (int c = 0; c < 512; ++c) a += vs[c] * xp[(size_t)c * N_];
    part[((size_t)sl * 64 + bh) * N_ + threadIdx.x] = a;
}

__global__ __launch_bounds__(256) void k_score(const float* __restrict__ part, const float* __restrict__ cst,
                                               float* __restrict__ score, float* __restrict__ out0) {
    const int b = blockIdx.x, k = threadIdx.x;
    const float scale = 0.044194173824159216f;
    float a[4];
#pragma unroll
    for (int h = 0; h < 4; ++h) {
        const int bh = b * 4 + h;
        float s = cst[bh];
#pragma unroll
        for (int sl = 0; sl < 4; ++sl) s += part[((size_t)sl * 64 + bh) * N_ + k];
        a[h] = s * scale;
    }
    float mx = fmaxf(fmaxf(a[0], a[1]), fmaxf(a[2], a[3]));
    float e0 = expf(a[0] - mx), e1 = expf(a[1] - mx), e2 = expf(a[2] - mx), e3 = expf(a[3] - mx);
    float inv = 1.0f / (e0 + e1 + e2 + e3);
    float r[4] = { e0 * inv, e1 * inv, e2 * inv, e3 * inv };
#pragma unroll
    for (int h = 0; h < 4; ++h) {
        score[(size_t)(b * 4 + h) * N_ + k] = r[h];
        out0[(size_t)(b * 4 + h) * N_ + k] = r[h];
    }
}

// ---------------- fp8 MFMA GEMMs ----------------
// proj: M=(b,n)=4096, N=(qk,h,d)=4096, K=2048 (256-core).
__global__ __launch_bounds__(512, 2) void k_proj(const u8* __restrict__ xbT8,
                                                 const u8* __restrict__ qw8, const u8* __restrict__ kw8,
                                                 const float* __restrict__ qb, const float* __restrict__ kb,
                                                 ushort_t* __restrict__ QKbuf) {
    __shared__ __align__(16) ldsf8_t lds;
    const int wg = xcd_swz(blockIdx.x, 256);
    const int quad = wg >> 2;
    const int mt = quad >> 2;                 // 0..15
    const int nt = (quad & 3) * 4 + (wg & 3); // 0..15
    const int c0 = nt * 256;
    const int qk = c0 >> 11;
    const int rem = c0 & 2047;                // h*512 + d0
    const u8* A  = xbT8 + (size_t)mt * 256 * C_;
    const u8* Bm = (qk ? kw8 : qw8) + (size_t)rem * C_;
    const float* bias  = (qk ? kb : qb) + rem;
    const int K = C_;

    fx4 acc[8][4];
#pragma unroll
    for (int i = 0; i < 8; ++i)
#pragma unroll
        for (int j = 0; j < 4; ++j) acc[i][j] = (fx4){0.f, 0.f, 0.f, 0.f};
    gemm256_f8(A, Bm, K, lds, acc);

    EPI256_IDX();
#pragma unroll
    for (int i = 0; i < 8; ++i)
#pragma unroll
        for (int n = 0; n < 4; ++n)
#pragma unroll
            for (int r = 0; r < 4; ++r) {
                const int gr = mt * 256 + wmr + i * 16 + lhi * 4 + r;
                const int bq = gr >> 8, nn = gr & 255;
                const int lc = wnr + n * 16 + l16;
                const int hh = (rem + lc) >> 9, dl = (rem + lc) & 511;
                const float v = acc[i][n][r] * (1.0f / 512.0f) + bias[lc];
                QKbuf[((((size_t)(qk * 16 + bq) * 4 + hh) * 256) + nn) * 512 + dl] = f2bs(v);
            }
}

// out: per h, M=e=2048, N=(b,n)=4096, K=2048. 128x256-core, 1024 wg x 512 thr, 2 blocks/CU.
__global__ __launch_bounds__(512, 4) void k_out(const u8* __restrict__ vw8, const float* __restrict__ vb,
                                                const u8* __restrict__ Tt8, const float* __restrict__ score,
                                                const ushort_t* __restrict__ xb, float* __restrict__ out1) {
    __shared__ __align__(16) ldsA_t ldsA;
    __shared__ __align__(16) ldsB_t2 ldsB;
    const int wg = xcd_swz(blockIdx.x, 1024);
    const int h = wg >> 8, l = wg & 255;
    const int mt = l >> 4, nt = l & 15;       // mt 0..15 (M=2048/128), nt 0..15 (N=4096/256)
    const u8* A  = vw8 + (size_t)h * C_ * C_ + (size_t)mt * 128 * C_;
    const u8* Bm = Tt8 + (size_t)h * 16 * N_ * C_ + (size_t)nt * 256 * C_;
    const int K = C_;

    fx4 acc[4][4];
#pragma unroll
    for (int i = 0; i < 4; ++i)
#pragma unroll
        for (int j = 0; j < 4; ++j) acc[i][j] = (fx4){0.f, 0.f, 0.f, 0.f};
    gemm128x256_f8(A, Bm, K, ldsA, ldsB, acc);

    const int lane = threadIdx.x & 63, w = threadIdx.x >> 6;
    const int l16 = lane & 15, lhi = lane >> 4;
    const int wma = (w >> 2) * 64, wnb = (w & 3) * 64;
#pragma unroll
    for (int i = 0; i < 4; ++i)
#pragma unroll
        for (int n = 0; n < 4; ++n)
#pragma unroll
            for (int r = 0; r < 4; ++r) {
                const int e = mt * 128 + wma + i * 16 + lhi * 4 + r;
                const int col = nt * 256 + wnb + n * 16 + l16;
                const int b = col >> 8, nn = col & 255;
                float v = acc[i][n][r] * (1.0f / 1024.0f) + vb[h * C_ + e]
                        + score[(size_t)(b * 4 + h) * N_ + nn] * bs2f(xb[((size_t)b * C_ + e) * N_ + nn]);
                out1[((size_t)(b * 4 + h) * C_ + e) * N_ + nn] = v;
            }
}

// T: per b, M=(h,q)=1024, N=c=2048, K=256 (256-core).
__global__ __launch_bounds__(512, 2) void k_T8(const u8* __restrict__ Pb8, const u8* __restrict__ xb8,
                                               u8* __restrict__ Tt8) {
    __shared__ __align__(16) ldsf8_t lds;
    const int wg = xcd_swz(blockIdx.x, 512);
    const int b = wg >> 5, l = wg & 31;       // 16 b x (4 mt x 8 nt)
    const int mt = l >> 3, nt = l & 7;
    const u8* A  = Pb8 + ((size_t)b * 1024 + mt * 256) * 256;
    const u8* Bm = xb8 + ((size_t)b * 2048 + nt * 256) * 256;
    const int K = N_;

    fx4 acc[8][4];
#pragma unroll
    for (int i = 0; i < 8; ++i)
#pragma unroll
        for (int j = 0; j < 4; ++j) acc[i][j] = (fx4){0.f, 0.f, 0.f, 0.f};
    gemm256_f8(A, Bm, K, lds, acc);

    EPI256_IDX();
#pragma unroll
    for (int i = 0; i < 8; ++i)
#pragma unroll
        for (int n = 0; n < 4; ++n)
#pragma unroll
            for (int r = 0; r < 4; ++r) {
                const int rowm = mt * 256 + wmr + i * 16 + lhi * 4 + r;
                const int h = rowm >> 8, q = rowm & 255;
                const int c = nt * 256 + wnr + n * 16 + l16;
                Tt8[(((size_t)h * 16 + b) * 256 + q) * 2048 + c] = f2f8(acc[i][n][r] * 0.0078125f);
            }
}

// sim: per bh, 128x128 tiles, K=512 (bf16 2-phase core). simf f32.
__global__ __launch_bounds__(256) void k_sim(const ushort_t* __restrict__ QKbuf, float* __restrict__ simf) {
    const int wg = blockIdx.x;
    const int bh = wg >> 2, mt = (wg >> 1) & 1, ntl = wg & 1;
    const ushort_t* Qr = QKbuf;
    const ushort_t* Kr = QKbuf + (size_t)16 * 4 * 256 * 512;
    const ushort_t* A = Qr + ((size_t)bh * 256 + mt * 128) * 512;
    const ushort_t* Bm = Kr + ((size_t)bh * 256 + ntl * 128) * 512;

    fx4 acc[4][4];
#pragma unroll
    for (int i = 0; i < 4; ++i)
#pragma unroll
        for (int j = 0; j < 4; ++j) acc[i][j] = (fx4){0.f, 0.f, 0.f, 0.f};
    mfma_core(A, Bm, D_, acc);

    EPI_IDX();
    const float scale = 0.044194173824159216f;
#pragma unroll
    for (int i = 0; i < 4; ++i)
#pragma unroll
        for (int j = 0; j < 4; ++j)
#pragma unroll
            for (int r = 0; r < 4; ++r) {
                const int q = mt * 128 + wm + i * 16 + lhi * 4 + r;
                const int k = ntl * 128 + wn + j * 16 + l16;
                simf[(size_t)bh * N_ * N_ + (size_t)q * N_ + k] = acc[i][j][r] * scale;
            }
}

__global__ __launch_bounds__(64) void k_softP(const float* __restrict__ simf, u8* __restrict__ Pb8) {
    const size_t row = blockIdx.x;
    const float* p = simf + row * N_;
    u8* o = Pb8 + row * N_;
    const int t = threadIdx.x;
    float v0 = p[t], v1 = p[t + 64], v2 = p[t + 128], v3 = p[t + 192];
    float mx = fmaxf(fmaxf(v0, v1), fmaxf(v2, v3));
#pragma unroll
    for (int off = 32; off; off >>= 1) mx = fmaxf(mx, __shfl_xor(mx, off, 64));
    float e0 = expf(v0 - mx), e1 = expf(v1 - mx), e2 = expf(v2 - mx), e3 = expf(v3 - mx);
    float s = e0 + e1 + e2 + e3;
#pragma unroll
    for (int off = 32; off; off >>= 1) s += __shfl_xor(s, off, 64);
    const float inv = 256.0f / s;     // store P * 256 as fp8
    o[t] = f2f8(e0 * inv); o[t + 64] = f2f8(e1 * inv);
    o[t + 128] = f2f8(e2 * inv); o[t + 192] = f2f8(e3 * inv);
}

extern "C" void kernel_launch(void* const* d_in, const int* in_sizes, int n_in,
                              void* d_out, int out_size, void* d_ws, size_t ws_size,
                              hipStream_t stream)
{
    const float* x  = (const float*)d_in[0];
    const float* qw = (const float*)d_in[1];
    const float* qb = (const float*)d_in[2];
    const float* kw = (const float*)d_in[3];
    const float* kb = (const float*)d_in[4];
    const float* vw = (const float*)d_in[5];
    const float* vb = (const float*)d_in[6];

    float* out0 = (float*)d_out;
    float* out1 = out0 + (size_t)B_ * HEADS_ * N_;

    char* w = (char*)d_ws;
    u8*       vw8  = (u8*)w;        w += (size_t)4 * C_ * C_;              // 16.8MB
    u8*       qw8  = (u8*)w;        w += (size_t)4 * D_ * C_;              // 4.2MB
    u8*       kw8  = (u8*)w;        w += (size_t)4 * D_ * C_;              // 4.2MB
    ushort_t* xb   = (ushort_t*)w;  w += (size_t)B_ * C_ * N_ * 2;         // 16.8MB (bf16, gating)
    u8*       xb8  = (u8*)w;        w += (size_t)B_ * C_ * N_;             // 8.4MB
    u8*       xbT8 = (u8*)w;        w += (size_t)B_ * N_ * C_;             // 8.4MB
    ushort_t* QKbuf= (ushort_t*)w;  w += (size_t)2 * 16 * 4 * 256 * 512 * 2; // 33.6MB bf16
    u8*       Pb8  = (u8*)w;        w += (size_t)64 * N_ * N_;             // 4.2MB
    float*    simf = (float*)w;     w += (size_t)64 * N_ * N_ * 4;         // 16.8MB
    u8*       Tt8  = (u8*)w;        w += (size_t)64 * N_ * C_;             // 33.6MB
    float*    xpart= (float*)w;     w += (size_t)8 * B_ * C_ * 4;          // 1MB
    float*    xsum = (float*)w;     w += (size_t)B_ * C_ * 4;
    float*    qsum = (float*)w;     w += (size_t)64 * D_ * 4;
    float*    cst  = (float*)w;     w += 1024;
    float*    partv= (float*)w;     w += (size_t)4 * 64 * C_ * 4;          // 2.1MB
    float*    part = (float*)w;     w += (size_t)4 * 64 * N_ * 4;
    float*    score= (float*)w;     w += (size_t)64 * N_ * 4;

    // casts (weights x64 -> fp8; x -> bf16 + fp8 x8 + transposed fp8 x8)
    k_castw8<<<dim3(4 * D_ * C_ / 4 / 256), 256, 0, stream>>>(qw, qw8, 4 * D_ * C_, 64.0f);
    k_castw8<<<dim3(4 * D_ * C_ / 4 / 256), 256, 0, stream>>>(kw, kw8, 4 * D_ * C_, 64.0f);
    k_castw8<<<dim3(4 * C_ * C_ / 4 / 256), 256, 0, stream>>>(vw, vw8, 4 * C_ * C_, 64.0f);
    k_cast_x<<<dim3(8, 64, 16), 256, 0, stream>>>(x, xb, xb8, xbT8, xpart);

    // exact-f32 score path
    k_xsum2<<<dim3(8, 16), 256, 0, stream>>>(xpart, xsum);
    k_qsum <<<dim3(512), 256, 0, stream>>>(xsum, qw, qb, qsum);
    k_const<<<dim3(64), 64, 0, stream>>>(qsum, kb, cst);
    k_vecp <<<dim3(8, 4, 4), 256, 0, stream>>>(qsum, kw, partv);
    k_att  <<<dim3(64, 4), 256, 0, stream>>>(x, partv, part);
    k_score<<<dim3(16), 256, 0, stream>>>(part, cst, score, out0);

    // MFMA pipeline
    k_proj <<<dim3(256), 512, 0, stream>>>(xbT8, qw8, kw8, qb, kb, QKbuf);
    k_sim  <<<dim3(256), 256, 0, stream>>>(QKbuf, simf);
    k_softP<<<dim3(64 * N_), 64, 0, stream>>>(simf, Pb8);
    k_T8   <<<dim3(512), 512, 0, stream>>>(Pb8, xb8, Tt8);
    k_out  <<<dim3(1024), 512, 0, stream>>>(vw8, vb, Tt8, score, xb, out1);
}

// Round 15
// 360.116 us; speedup vs baseline: 1.8590x; 1.0006x over previous
//
#include <hip/hip_runtime.h>
#include <hip/hip_bf16.h>
#include <hip/hip_fp8.h>

#define B_ 16
#define C_ 2048
#define N_ 256
#define HEADS_ 4
#define D_ 512

typedef unsigned int u32;
typedef unsigned char u8;
typedef unsigned short ushort_t;
typedef __attribute__((ext_vector_type(8))) short bfx8;
typedef __attribute__((ext_vector_type(4))) float fx4;

__device__ __forceinline__ unsigned short f2bs(float f) {
    __hip_bfloat16 h = __float2bfloat16(f);
    return __builtin_bit_cast(unsigned short, h);
}
__device__ __forceinline__ float bs2f(ushort_t u) {
    u32 v = ((u32)u) << 16;
    return __builtin_bit_cast(float, v);
}
__device__ __forceinline__ u8 f2f8(float f) {
    return (u8)__hip_cvt_float_to_fp8(f, __HIP_SATFINITE, __HIP_E4M3);
}
__device__ __forceinline__ void gload16(const void* g, void* l) {
    __builtin_amdgcn_global_load_lds((const __attribute__((address_space(1))) u32*)g,
                                     (__attribute__((address_space(3))) u32*)l, 16, 0, 0);
}
__device__ __forceinline__ int xcd_swz(int bid, int nwg) {
    return (bid & 7) * (nwg >> 3) + (bid >> 3);
}

#define SBAR() __builtin_amdgcn_s_barrier()
#define LGKM0() do { asm volatile("s_waitcnt lgkmcnt(0)" ::: "memory"); \
                     __builtin_amdgcn_sched_barrier(0); } while (0)
#define VMW3() asm volatile("s_waitcnt vmcnt(3)" ::: "memory")
#define VMW2() asm volatile("s_waitcnt vmcnt(2)" ::: "memory")
#define VMW1() asm volatile("s_waitcnt vmcnt(1)" ::: "memory")

// ============ 128x256 merged-phase fp8 core: 2 blocks/CU for cross-block overlap ============
// NT GEMM fp8 e4m3: C tile 128(A-rows) x 256(B-rows), 512 thr = 8 waves (2Mw x 4Nw),
// wave tile 64x64, acc[4][4] = 64 AGPR. LDS 48 KiB (A 16KB dbuf + B 32KB dbuf) ->
// 2-3 blocks/CU at <=128 unified regs (__launch_bounds__(512,4)).
// Regions/K-tile(64): RA = A both kh (waves 0-3 kh0, 4-7 kh1, 1 gload/thr),
// RB0/RB1 = B per kh (1 gload/thr). 2 phases/tile:
//   ph0: read kh0 frags; stage RA(j+1), RB1(j+1); bar; lgkm0; 16 MFMA; vmcnt(3); bar
//   ph1: read kh1 frags; stage RB0(j+2);          bar; lgkm0; 16 MFMA; vmcnt(2); bar
// FIFO audit: ph0-end needs RA(j)/RB1(j) [staged j-1 ph0] -> 3 younger outstanding;
// ph1-end needs RA(j+1) [j ph0] -> 2 younger (RB1(j+1), RB0(j+2)). Prologue: RA(0),
// RB0(0), RB1(0), RB0(1) then vmcnt(1). Tail clamps are dead re-stages (counts exact).
// Bank swizzle (both sides): source k-octet ^ ((tid>>3)&1)*16; read slot = f8off involution.
#define STGA2(BUF, J) do {                                                    \
    const int t_ = tid & 255;                                                 \
    const int kh_ = tid >> 8;                                                 \
    const int r_ = t_ >> 1;                                                   \
    const int k_ = (J) * 64 + kh_ * 32 + (((tid & 1) ^ ((tid >> 3) & 1)) * 16); \
    gload16(A + (size_t)r_ * K + k_,                                          \
            (u8*)(&ldsA[BUF][kh_][0][0]) + t_ * 16);                          \
} while (0)

#define STGB2(BUF, KH, J) do {                                                \
    const int r_ = tid >> 1;                                                  \
    const int k_ = (J) * 64 + (KH) * 32 + (((tid & 1) ^ ((tid >> 3) & 1)) * 16); \
    gload16(Bm + (size_t)r_ * K + k_,                                         \
            (u8*)(&ldsB[BUF][KH][0][0]) + tid * 16);                          \
} while (0)

#define LDA2(dst, BUF, KH) do {                                               \
    _Pragma("unroll")                                                         \
    for (int i_ = 0; i_ < 4; ++i_)                                            \
        dst[i_] = *(const long*)(&ldsA[BUF][KH][wma + i_ * 16 + l16][f8off]); \
} while (0)

#define LDB2(dst, BUF, KH) do {                                               \
    _Pragma("unroll")                                                         \
    for (int i_ = 0; i_ < 4; ++i_)                                            \
        dst[i_] = *(const long*)(&ldsB[BUF][KH][wnb + i_ * 16 + l16][f8off]); \
} while (0)

#define MM16W(aa, bb) do {                                                    \
    __builtin_amdgcn_s_setprio(1);                                            \
    _Pragma("unroll")                                                         \
    for (int i_ = 0; i_ < 4; ++i_) {                                          \
        _Pragma("unroll")                                                     \
        for (int n_ = 0; n_ < 4; ++n_)                                        \
            acc[i_][n_] = __builtin_amdgcn_mfma_f32_16x16x32_fp8_fp8(         \
                aa[i_], bb[n_], acc[i_][n_], 0, 0, 0);                        \
    }                                                                         \
    __builtin_amdgcn_s_setprio(0);                                            \
} while (0)

#define KTW(BUF, JS1, JS2) do {                                               \
    long a0[4], b0[4];                                                        \
    /* ph0 (kh0) */                                                           \
    LDA2(a0, BUF, 0); LDB2(b0, BUF, 0);                                       \
    STGA2(BUF ^ 1, JS1);                                                      \
    STGB2(BUF ^ 1, 1, JS1);                                                   \
    SBAR(); LGKM0();                                                          \
    MM16W(a0, b0);                                                            \
    VMW3();                                                                   \
    SBAR();                                                                   \
    /* ph1 (kh1) */                                                           \
    LDA2(a0, BUF, 1); LDB2(b0, BUF, 1);                                       \
    STGB2(BUF, 0, JS2);                                                       \
    SBAR(); LGKM0();                                                          \
    MM16W(a0, b0);                                                            \
    VMW2();                                                                   \
    SBAR();                                                                   \
} while (0)

typedef u8 ldsA_t[2][2][128][32];   // 16 KiB
typedef u8 ldsB_t2[2][2][256][32];  // 32 KiB

__device__ __forceinline__ void gemm128x256_f8(const u8* __restrict__ A,
                                               const u8* __restrict__ Bm,
                                               int K, ldsA_t& ldsA, ldsB_t2& ldsB,
                                               fx4 acc[4][4])
{
    const int tid = threadIdx.x;       // 0..511
    const int lane = tid & 63;
    const int w = tid >> 6;            // 0..7
    const int l16 = lane & 15, lhi = lane >> 4;
    const int f8off = (((lhi >> 1) ^ ((l16 >> 2) & 1)) * 16) + (lhi & 1) * 8;
    const int wma = (w >> 2) * 64;     // A rows (128 total, 2 M-waves)
    const int wnb = (w & 3) * 64;      // B rows (256 total, 4 N-waves)
    const int nkt = K >> 6;            // even, >= 4

    // prologue: RA(0), RB0(0), RB1(0), RB0(1); tile0 ready when 1 outstanding.
    STGA2(0, 0);
    STGB2(0, 0, 0);
    STGB2(0, 1, 0);
    STGB2(1, 0, 1);
    VMW1();
    SBAR();

    for (int jj = 0; jj < nkt; jj += 2) {
        const int js1a = jj + 1;                              // < nkt always
        const int js2a = (jj + 2 < nkt) ? jj + 2 : nkt - 1;
        const int js1b = js2a;
        const int js2b = (jj + 3 < nkt) ? jj + 3 : nkt - 1;
        KTW(0, js1a, js2a);
        KTW(1, js1b, js2b);
    }
    asm volatile("s_waitcnt vmcnt(0)" ::: "memory");
    SBAR();
}

#define EPI128_IDX() \
    const int lane = threadIdx.x & 63, w = threadIdx.x >> 6; \
    const int l16 = lane & 15, lhi = lane >> 4; \
    const int wma = (w >> 2) * 64, wnb = (w & 3) * 64;

// ---------------- 128x128 2-phase bf16 core (k_sim only), T2-swizzled ----------------
__device__ __forceinline__ void mfma_core(const ushort_t* __restrict__ A,
                                          const ushort_t* __restrict__ Bm,
                                          int K, fx4 acc[4][4])
{
    __shared__ __align__(16) ushort_t As[128 * 32];
    __shared__ __align__(16) ushort_t Bs[128 * 32];
    const int tid = threadIdx.x;
    const int lane = tid & 63, wave = tid >> 6;
    const int l16 = lane & 15, lhi = lane >> 4;
    const int swz8 = (lhi ^ ((l16 >> 1) & 3)) * 8;
    const int wm = (wave >> 1) * 64, wn = (wave & 1) * 64;

    for (int k0 = 0; k0 < K; k0 += 32) {
        const int f0 = tid, f1 = tid + 256;
        gload16(A + (size_t)(f0 >> 2) * K + k0 + (((f0 & 3) ^ ((f0 >> 3) & 3)) * 8), As + f0 * 8);
        gload16(A + (size_t)(f1 >> 2) * K + k0 + (((f1 & 3) ^ ((f1 >> 3) & 3)) * 8), As + f1 * 8);
        gload16(Bm + (size_t)(f0 >> 2) * K + k0 + (((f0 & 3) ^ ((f0 >> 3) & 3)) * 8), Bs + f0 * 8);
        gload16(Bm + (size_t)(f1 >> 2) * K + k0 + (((f1 & 3) ^ ((f1 >> 3) & 3)) * 8), Bs + f1 * 8);
        __syncthreads();
        bfx8 af[4], bfr[4];
#pragma unroll
        for (int i = 0; i < 4; ++i)
            af[i] = *(const bfx8*)(As + (wm + i * 16 + l16) * 32 + swz8);
#pragma unroll
        for (int j = 0; j < 4; ++j)
            bfr[j] = *(const bfx8*)(Bs + (wn + j * 16 + l16) * 32 + swz8);
#pragma unroll
        for (int i = 0; i < 4; ++i)
#pragma unroll
            for (int j = 0; j < 4; ++j)
                acc[i][j] = __builtin_amdgcn_mfma_f32_16x16x32_bf16(af[i], bfr[j], acc[i][j], 0, 0, 0);
        __syncthreads();
    }
}

#define EPI_IDX() \
    const int lane = threadIdx.x & 63, wave = threadIdx.x >> 6; \
    const int l16 = lane & 15, lhi = lane >> 4; \
    const int wm = (wave >> 1) * 64, wn = (wave & 1) * 64;

// ---------------- casts ----------------
__global__ __launch_bounds__(256) void k_castw8(const float* __restrict__ s, u8* __restrict__ d,
                                                int n, float scale) {
    int i = (blockIdx.x * 256 + threadIdx.x) * 4;
    if (i >= n) return;
    float4 v = *(const float4*)(s + i);
    uchar4 o = { f2f8(v.x * scale), f2f8(v.y * scale), f2f8(v.z * scale), f2f8(v.w * scale) };
    *(uchar4*)(d + i) = o;
}

__global__ __launch_bounds__(256) void k_cast_x(const float* __restrict__ x,
                                                ushort_t* __restrict__ xb, u8* __restrict__ xb8,
                                                u8* __restrict__ xbT8, float* __restrict__ xpart) {
    __shared__ float t[32][33];
    const int b = blockIdx.z, c0 = blockIdx.y * 32, n0 = blockIdx.x * 32;
    const int tn = threadIdx.x & 31, tc8 = threadIdx.x >> 5;
    const float* xp = x + ((size_t)b * C_ + c0) * N_ + n0;
#pragma unroll
    for (int p = 0; p < 4; ++p) {
        int cc = tc8 + p * 8;
        float v = xp[(size_t)cc * N_ + tn];
        t[cc][tn] = v;
        xb[((size_t)b * C_ + c0 + cc) * N_ + n0 + tn] = f2bs(v);
        xb8[((size_t)b * C_ + c0 + cc) * N_ + n0 + tn] = f2f8(v * 8.0f);
        float s = v;
#pragma unroll
        for (int o = 16; o; o >>= 1) s += __shfl_xor(s, o, 32);
        if (tn == 0) xpart[(size_t)blockIdx.x * B_ * C_ + (size_t)b * C_ + c0 + cc] = s;
    }
    __syncthreads();
#pragma unroll
    for (int p = 0; p < 4; ++p) {
        int nn = tc8 + p * 8;
        xbT8[((size_t)b * N_ + n0 + nn) * C_ + c0 + tn] = f2f8(t[tn][nn] * 8.0f);
    }
}

__global__ __launch_bounds__(256) void k_xsum2(const float* __restrict__ xpart, float* __restrict__ xsum) {
    const int c = blockIdx.x * 256 + threadIdx.x, b = blockIdx.y;
    float s = 0.f;
#pragma unroll
    for (int t = 0; t < 8; ++t) s += xpart[(size_t)t * B_ * C_ + (size_t)b * C_ + c];
    xsum[(size_t)b * C_ + c] = s;
}

// ---------------- exact-f32 score path ----------------
__global__ __launch_bounds__(256) void k_qsum(const float* __restrict__ xsum, const float* __restrict__ qw,
                                              const float* __restrict__ qb, float* __restrict__ qsum) {
    const int wave = threadIdx.x >> 6, lane = threadIdx.x & 63;
    const int row = blockIdx.x * 4 + wave;            // h*512+d, in [0, 2048)
    const int h = row >> 9, d = row & 511;
    const float* wr = qw + (size_t)row * C_;
    float acc[16];
#pragma unroll
    for (int bb = 0; bb < 16; ++bb) acc[bb] = 0.f;
    for (int it = 0; it < C_ / 64; ++it) {
        const int c = it * 64 + lane;
        const float w = wr[c];
#pragma unroll
        for (int bb = 0; bb < 16; ++bb) acc[bb] += xsum[(size_t)bb * C_ + c] * w;
    }
#pragma unroll
    for (int bb = 0; bb < 16; ++bb) {
        float s = acc[bb];
#pragma unroll
        for (int o = 32; o; o >>= 1) s += __shfl_xor(s, o, 64);
        if (lane == 0) qsum[(size_t)((bb << 2) | h) * D_ + d] = s + 256.0f * qb[row];
    }
}

__global__ __launch_bounds__(64) void k_const(const float* __restrict__ qsum, const float* __restrict__ kb,
                                              float* __restrict__ cst) {
    const int bh = blockIdx.x, h = bh & 3, lane = threadIdx.x;
    float s = 0.f;
    for (int d = lane; d < D_; d += 64) s += qsum[(size_t)bh * D_ + d] * kb[h * D_ + d];
#pragma unroll
    for (int o = 32; o; o >>= 1) s += __shfl_xor(s, o, 64);
    if (lane == 0) cst[bh] = s;
}

__global__ __launch_bounds__(256) void k_vecp(const float* __restrict__ qsum, const float* __restrict__ kw,
                                              float* __restrict__ partv) {
    const int ct = blockIdx.x, h = blockIdx.y, dsl = blockIdx.z;
    __shared__ float qs[16 * 128];
    for (int i = threadIdx.x; i < 16 * 128; i += 256) {
        int bb = i >> 7, dd = i & 127;
        qs[i] = qsum[(size_t)((bb << 2) | h) * D_ + dsl * 128 + dd];
    }
    __syncthreads();
    const int c = ct * 256 + threadIdx.x;
    const float* wp = kw + ((size_t)h * D_ + dsl * 128) * C_ + c;
    float acc[16];
#pragma unroll
    for (int bb = 0; bb < 16; ++bb) acc[bb] = 0.f;
    for (int dd = 0; dd < 128; ++dd) {
        const float w = wp[(size_t)dd * C_];
#pragma unroll
        for (int bb = 0; bb < 16; ++bb) acc[bb] += qs[bb * 128 + dd] * w;
    }
#pragma unroll
    for (int bb = 0; bb < 16; ++bb)
        partv[((size_t)dsl * 64 + ((bb << 2) | h)) * C_ + c] = acc[bb];
}

__global__ __launch_bounds__(256) void k_att(const float* __restrict__ x, const float* __restrict__ partv,
                                             float* __restrict__ part) {
    const int bh = blockIdx.x, sl = blockIdx.y, b = bh >> 2;
    __shared__ float vs[512];
    const int c0 = sl * 512;
    for (int i = threadIdx.x; i < 512; i += 256) {
        float v = 0.f;
#pragma unroll
        for (int dsl = 0; dsl < 4; ++dsl) v += partv[((size_t)dsl * 64 + bh) * C_ + c0 + i];
        vs[i] = v;
    }
    __syncthreads();
    float a = 0.f;
    const float* xp = x + ((size_t)b * C_ + c0) * N_ + threadIdx.x;
#pragma unroll 8
    for (int c = 0; c < 512; ++c) a += vs[c] * xp[(size_t)c * N_];
    part[((size_t)sl * 64 + bh) * N_ + threadIdx.x] = a;
}

__global__ __launch_bounds__(256) void k_score(const float* __restrict__ part, const float* __restrict__ cst,
                                               float* __restrict__ score, float* __restrict__ out0) {
    const int b = blockIdx.x, k = threadIdx.x;
    const float scale = 0.044194173824159216f;
    float a[4];
#pragma unroll
    for (int h = 0; h < 4; ++h) {
        const int bh = b * 4 + h;
        float s = cst[bh];
#pragma unroll
        for (int sl = 0; sl < 4; ++sl) s += part[((size_t)sl * 64 + bh) * N_ + k];
        a[h] = s * scale;
    }
    float mx = fmaxf(fmaxf(a[0], a[1]), fmaxf(a[2], a[3]));
    float e0 = expf(a[0] - mx), e1 = expf(a[1] - mx), e2 = expf(a[2] - mx), e3 = expf(a[3] - mx);
    float inv = 1.0f / (e0 + e1 + e2 + e3);
    float r[4] = { e0 * inv, e1 * inv, e2 * inv, e3 * inv };
#pragma unroll
    for (int h = 0; h < 4; ++h) {
        score[(size_t)(b * 4 + h) * N_ + k] = r[h];
        out0[(size_t)(b * 4 + h) * N_ + k] = r[h];
    }
}

// ---------------- fp8 MFMA GEMMs (all on the 128x256 2-block/CU core) ----------------
// proj: M=(b,n)=4096, N=(qk,h,d)=4096, K=2048. 512 wg x 512 thr.
__global__ __launch_bounds__(512, 4) void k_proj(const u8* __restrict__ xbT8,
                                                 const u8* __restrict__ qw8, const u8* __restrict__ kw8,
                                                 const float* __restrict__ qb, const float* __restrict__ kb,
                                                 ushort_t* __restrict__ QKbuf) {
    __shared__ __align__(16) ldsA_t ldsA;
    __shared__ __align__(16) ldsB_t2 ldsB;
    const int wg = xcd_swz(blockIdx.x, 512);
    const int mt = wg >> 4;                   // 0..31
    const int nt = wg & 15;                   // 0..15
    const int c0 = nt * 256;
    const int qk = c0 >> 11;
    const int rem = c0 & 2047;                // h*512 + d0 range start
    const u8* A  = xbT8 + (size_t)mt * 128 * C_;
    const u8* Bm = (qk ? kw8 : qw8) + (size_t)rem * C_;
    const float* bias  = (qk ? kb : qb) + rem;
    const int K = C_;

    fx4 acc[4][4];
#pragma unroll
    for (int i = 0; i < 4; ++i)
#pragma unroll
        for (int j = 0; j < 4; ++j) acc[i][j] = (fx4){0.f, 0.f, 0.f, 0.f};
    gemm128x256_f8(A, Bm, K, ldsA, ldsB, acc);

    EPI128_IDX();
#pragma unroll
    for (int i = 0; i < 4; ++i)
#pragma unroll
        for (int n = 0; n < 4; ++n)
#pragma unroll
            for (int r = 0; r < 4; ++r) {
                const int gr = mt * 128 + wma + i * 16 + lhi * 4 + r;
                const int bq = gr >> 8, nn = gr & 255;
                const int lc = wnb + n * 16 + l16;
                const int hh = (rem + lc) >> 9, dl = (rem + lc) & 511;
                const float v = acc[i][n][r] * (1.0f / 512.0f) + bias[lc];
                QKbuf[((((size_t)(qk * 16 + bq) * 4 + hh) * 256) + nn) * 512 + dl] = f2bs(v);
            }
}

// out: per h, M=e=2048, N=(b,n)=4096, K=2048. 1024 wg x 512 thr.
__global__ __launch_bounds__(512, 4) void k_out(const u8* __restrict__ vw8, const float* __restrict__ vb,
                                                const u8* __restrict__ Tt8, const float* __restrict__ score,
                                                const ushort_t* __restrict__ xb, float* __restrict__ out1) {
    __shared__ __align__(16) ldsA_t ldsA;
    __shared__ __align__(16) ldsB_t2 ldsB;
    const int wg = xcd_swz(blockIdx.x, 1024);
    const int h = wg >> 8, l = wg & 255;
    const int mt = l >> 4, nt = l & 15;       // mt 0..15 (M=2048/128), nt 0..15 (N=4096/256)
    const u8* A  = vw8 + (size_t)h * C_ * C_ + (size_t)mt * 128 * C_;
    const u8* Bm = Tt8 + (size_t)h * 16 * N_ * C_ + (size_t)nt * 256 * C_;
    const int K = C_;

    fx4 acc[4][4];
#pragma unroll
    for (int i = 0; i < 4; ++i)
#pragma unroll
        for (int j = 0; j < 4; ++j) acc[i][j] = (fx4){0.f, 0.f, 0.f, 0.f};
    gemm128x256_f8(A, Bm, K, ldsA, ldsB, acc);

    EPI128_IDX();
#pragma unroll
    for (int i = 0; i < 4; ++i)
#pragma unroll
        for (int n = 0; n < 4; ++n)
#pragma unroll
            for (int r = 0; r < 4; ++r) {
                const int e = mt * 128 + wma + i * 16 + lhi * 4 + r;
                const int col = nt * 256 + wnb + n * 16 + l16;
                const int b = col >> 8, nn = col & 255;
                float v = acc[i][n][r] * (1.0f / 1024.0f) + vb[h * C_ + e]
                        + score[(size_t)(b * 4 + h) * N_ + nn] * bs2f(xb[((size_t)b * C_ + e) * N_ + nn]);
                out1[((size_t)(b * 4 + h) * C_ + e) * N_ + nn] = v;
            }
}

// T: per b, M=(h,q)=1024, N=c=2048, K=256. 1024 wg x 512 thr (3 blocks/CU by LDS).
__global__ __launch_bounds__(512, 4) void k_T8(const u8* __restrict__ Pb8, const u8* __restrict__ xb8,
                                               u8* __restrict__ Tt8) {
    __shared__ __align__(16) ldsA_t ldsA;
    __shared__ __align__(16) ldsB_t2 ldsB;
    const int wg = xcd_swz(blockIdx.x, 1024);
    const int b = wg >> 6, l = wg & 63;       // 16 b x (8 mt x 8 nt)
    const int mt = l >> 3, nt = l & 7;
    const u8* A  = Pb8 + ((size_t)b * 1024 + mt * 128) * 256;
    const u8* Bm = xb8 + ((size_t)b * 2048 + nt * 256) * 256;
    const int K = N_;

    fx4 acc[4][4];
#pragma unroll
    for (int i = 0; i < 4; ++i)
#pragma unroll
        for (int j = 0; j < 4; ++j) acc[i][j] = (fx4){0.f, 0.f, 0.f, 0.f};
    gemm128x256_f8(A, Bm, K, ldsA, ldsB, acc);

    EPI128_IDX();
#pragma unroll
    for (int i = 0; i < 4; ++i)
#pragma unroll
        for (int n = 0; n < 4; ++n)
#pragma unroll
            for (int r = 0; r < 4; ++r) {
                const int rowm = mt * 128 + wma + i * 16 + lhi * 4 + r;
                const int h = rowm >> 8, q = rowm & 255;
                const int c = nt * 256 + wnb + n * 16 + l16;
                Tt8[(((size_t)h * 16 + b) * 256 + q) * 2048 + c] = f2f8(acc[i][n][r] * 0.0078125f);
            }
}

// sim: per bh, 128x128 tiles, K=512 (bf16 2-phase core). simf f32.
__global__ __launch_bounds__(256) void k_sim(const ushort_t* __restrict__ QKbuf, float* __restrict__ simf) {
    const int wg = blockIdx.x;
    const int bh = wg >> 2, mt = (wg >> 1) & 1, ntl = wg & 1;
    const ushort_t* Qr = QKbuf;
    const ushort_t* Kr = QKbuf + (size_t)16 * 4 * 256 * 512;
    const ushort_t* A = Qr + ((size_t)bh * 256 + mt * 128) * 512;
    const ushort_t* Bm = Kr + ((size_t)bh * 256 + ntl * 128) * 512;

    fx4 acc[4][4];
#pragma unroll
    for (int i = 0; i < 4; ++i)
#pragma unroll
        for (int j = 0; j < 4; ++j) acc[i][j] = (fx4){0.f, 0.f, 0.f, 0.f};
    mfma_core(A, Bm, D_, acc);

    EPI_IDX();
    const float scale = 0.044194173824159216f;
#pragma unroll
    for (int i = 0; i < 4; ++i)
#pragma unroll
        for (int j = 0; j < 4; ++j)
#pragma unroll
            for (int r = 0; r < 4; ++r) {
                const int q = mt * 128 + wm + i * 16 + lhi * 4 + r;
                const int k = ntl * 128 + wn + j * 16 + l16;
                simf[(size_t)bh * N_ * N_ + (size_t)q * N_ + k] = acc[i][j][r] * scale;
            }
}

__global__ __launch_bounds__(64) void k_softP(const float* __restrict__ simf, u8* __restrict__ Pb8) {
    const size_t row = blockIdx.x;
    const float* p = simf + row * N_;
    u8* o = Pb8 + row * N_;
    const int t = threadIdx.x;
    float v0 = p[t], v1 = p[t + 64], v2 = p[t + 128], v3 = p[t + 192];
    float mx = fmaxf(fmaxf(v0, v1), fmaxf(v2, v3));
#pragma unroll
    for (int off = 32; off; off >>= 1) mx = fmaxf(mx, __shfl_xor(mx, off, 64));
    float e0 = expf(v0 - mx), e1 = expf(v1 - mx), e2 = expf(v2 - mx), e3 = expf(v3 - mx);
    float s = e0 + e1 + e2 + e3;
#pragma unroll
    for (int off = 32; off; off >>= 1) s += __shfl_xor(s, off, 64);
    const float inv = 256.0f / s;     // store P * 256 as fp8
    o[t] = f2f8(e0 * inv); o[t + 64] = f2f8(e1 * inv);
    o[t + 128] = f2f8(e2 * inv); o[t + 192] = f2f8(e3 * inv);
}

extern "C" void kernel_launch(void* const* d_in, const int* in_sizes, int n_in,
                              void* d_out, int out_size, void* d_ws, size_t ws_size,
                              hipStream_t stream)
{
    const float* x  = (const float*)d_in[0];
    const float* qw = (const float*)d_in[1];
    const float* qb = (const float*)d_in[2];
    const float* kw = (const float*)d_in[3];
    const float* kb = (const float*)d_in[4];
    const float* vw = (const float*)d_in[5];
    const float* vb = (const float*)d_in[6];

    float* out0 = (float*)d_out;
    float* out1 = out0 + (size_t)B_ * HEADS_ * N_;

    char* w = (char*)d_ws;
    u8*       vw8  = (u8*)w;        w += (size_t)4 * C_ * C_;              // 16.8MB
    u8*       qw8  = (u8*)w;        w += (size_t)4 * D_ * C_;              // 4.2MB
    u8*       kw8  = (u8*)w;        w += (size_t)4 * D_ * C_;              // 4.2MB
    ushort_t* xb   = (ushort_t*)w;  w += (size_t)B_ * C_ * N_ * 2;         // 16.8MB (bf16, gating)
    u8*       xb8  = (u8*)w;        w += (size_t)B_ * C_ * N_;             // 8.4MB
    u8*       xbT8 = (u8*)w;        w += (size_t)B_ * N_ * C_;             // 8.4MB
    ushort_t* QKbuf= (ushort_t*)w;  w += (size_t)2 * 16 * 4 * 256 * 512 * 2; // 33.6MB bf16
    u8*       Pb8  = (u8*)w;        w += (size_t)64 * N_ * N_;             // 4.2MB
    float*    simf = (float*)w;     w += (size_t)64 * N_ * N_ * 4;         // 16.8MB
    u8*       Tt8  = (u8*)w;        w += (size_t)64 * N_ * C_;             // 33.6MB
    float*    xpart= (float*)w;     w += (size_t)8 * B_ * C_ * 4;          // 1MB
    float*    xsum = (float*)w;     w += (size_t)B_ * C_ * 4;
    float*    qsum = (float*)w;     w += (size_t)64 * D_ * 4;
    float*    cst  = (float*)w;     w += 1024;
    float*    partv= (float*)w;     w += (size_t)4 * 64 * C_ * 4;          // 2.1MB
    float*    part = (float*)w;     w += (size_t)4 * 64 * N_ * 4;
    float*    score= (float*)w;     w += (size_t)64 * N_ * 4;

    // casts (weights x64 -> fp8; x -> bf16 + fp8 x8 + transposed fp8 x8)
    k_castw8<<<dim3(4 * D_ * C_ / 4 / 256), 256, 0, stream>>>(qw, qw8, 4 * D_ * C_, 64.0f);
    k_castw8<<<dim3(4 * D_ * C_ / 4 / 256), 256, 0, stream>>>(kw, kw8, 4 * D_ * C_, 64.0f);
    k_castw8<<<dim3(4 * C_ * C_ / 4 / 256), 256, 0, stream>>>(vw, vw8, 4 * C_ * C_, 64.0f);
    k_cast_x<<<dim3(8, 64, 16), 256, 0, stream>>>(x, xb, xb8, xbT8, xpart);

    // exact-f32 score path
    k_xsum2<<<dim3(8, 16), 256, 0, stream>>>(xpart, xsum);
    k_qsum <<<dim3(512), 256, 0, stream>>>(xsum, qw, qb, qsum);
    k_const<<<dim3(64), 64, 0, stream>>>(qsum, kb, cst);
    k_vecp <<<dim3(8, 4, 4), 256, 0, stream>>>(qsum, kw, partv);
    k_att  <<<dim3(64, 4), 256, 0, stream>>>(x, partv, part);
    k_score<<<dim3(16), 256, 0, stream>>>(part, cst, score, out0);

    // MFMA pipeline (all 128x256 2-block/CU fp8 cores)
    k_proj <<<dim3(512), 512, 0, stream>>>(xbT8, qw8, kw8, qb, kb, QKbuf);
    k_sim  <<<dim3(256), 256, 0, stream>>>(QKbuf, simf);
    k_softP<<<dim3(64 * N_), 64, 0, stream>>>(simf, Pb8);
    k_T8   <<<dim3(1024), 512, 0, stream>>>(Pb8, xb8, Tt8);
    k_out  <<<dim3(1024), 512, 0, stream>>>(vw8, vb, Tt8, score, xb, out1);
}